// Round 1
// 394.278 us; speedup vs baseline: 1.0213x; 1.0213x over previous
//
#include <hip/hip_runtime.h>
#include <hip/hip_bf16.h>

#define N_NODES 50000
#define N_EDGES 800000
#define N_TOT   850000   // edges + self loops
#define MAXD    128      // LDS-staged edges per node; tail handled by fallback

typedef __hip_bfloat16 bf16;
typedef __attribute__((ext_vector_type(8))) short bf16x8;   // MFMA A/B frag (4 VGPRs)
typedef __attribute__((ext_vector_type(4))) float f32x4;    // MFMA C/D frag

__device__ __forceinline__ float b2f(bf16 v){ return __bfloat162float(v); }
__device__ __forceinline__ bf16  f2b(float v){ return __float2bfloat16(v); }
__device__ __forceinline__ unsigned short f2bu(float v){
  union { bf16 b; unsigned short u; } cv; cv.b = __float2bfloat16(v); return cv.u;
}
__device__ __forceinline__ float bflo(unsigned int d){ return __uint_as_float(d << 16); }
__device__ __forceinline__ float bfhi(unsigned int d){ return __uint_as_float(d & 0xffff0000u); }
__device__ __forceinline__ bf16x8 pack8(float4 a, float4 b){
  union { uint4 u; bf16x8 v; } r;
  r.u.x = (unsigned)f2bu(a.x) | ((unsigned)f2bu(a.y) << 16);
  r.u.y = (unsigned)f2bu(a.z) | ((unsigned)f2bu(a.w) << 16);
  r.u.z = (unsigned)f2bu(b.x) | ((unsigned)f2bu(b.y) << 16);
  r.u.w = (unsigned)f2bu(b.z) | ((unsigned)f2bu(b.w) << 16);
  return r.v;
}

// ---------------- CSR build (group edges by destination = col) ----------------
__global__ __launch_bounds__(256) void hist_kernel(const int* __restrict__ ei, int* __restrict__ cnt){
  int k = blockIdx.x*256 + threadIdx.x;
  if (k >= N_TOT) return;
  int c = (k < N_EDGES) ? ei[N_EDGES + k] : (k - N_EDGES);
  atomicAdd(&cnt[c], 1);
}

// hierarchical scan: A) per-1024-block sums  B) scan 49 partials  C) per-block scan + base
__global__ __launch_bounds__(1024) void scanA_kernel(const int* __restrict__ cnt, int* __restrict__ psum){
  __shared__ int wsum[16];
  int tid = threadIdx.x, i = blockIdx.x*1024 + tid;
  int v = (i < N_NODES) ? cnt[i] : 0;
  #pragma unroll
  for (int off = 32; off; off >>= 1) v += __shfl_xor(v, off, 64);
  if ((tid & 63) == 0) wsum[tid >> 6] = v;
  __syncthreads();
  if (tid < 64) {
    int t = (tid < 16) ? wsum[tid] : 0;
    #pragma unroll
    for (int off = 8; off; off >>= 1) t += __shfl_xor(t, off, 64);
    if (tid == 0) psum[blockIdx.x] = t;
  }
}

__global__ __launch_bounds__(64) void scanB_kernel(int* __restrict__ psum, int nparts){
  int lane = threadIdx.x;
  int v = (lane < nparts) ? psum[lane] : 0;
  #pragma unroll
  for (int off = 1; off < 64; off <<= 1) {
    int t = __shfl_up(v, off, 64);
    if (lane >= off) v += t;
  }
  int e = __shfl_up(v, 1, 64);
  if (lane == 0) e = 0;
  if (lane < nparts) psum[lane] = e;
}

__global__ __launch_bounds__(1024) void scanC_kernel(const int* __restrict__ cnt, const int* __restrict__ psum,
                                                     int* __restrict__ offs, int* __restrict__ cursor){
  __shared__ int sm[1024];
  int tid = threadIdx.x, b = blockIdx.x, i = b*1024 + tid;
  int v = (i < N_NODES) ? cnt[i] : 0;
  sm[tid] = v;
  __syncthreads();
  for (int off = 1; off < 1024; off <<= 1) {
    int t = (tid >= off) ? sm[tid - off] : 0;
    __syncthreads();
    sm[tid] += t;
    __syncthreads();
  }
  if (i < N_NODES) {
    int e = psum[b] + sm[tid] - v;
    offs[i] = e; cursor[i] = e;
  }
  if (b == 0 && tid == 0) offs[N_NODES] = N_TOT;
}

__global__ __launch_bounds__(256) void scatter_kernel(const int* __restrict__ ei,
                                                      int* __restrict__ cursor,
                                                      int* __restrict__ srcs){
  int k = blockIdx.x*256 + threadIdx.x;
  if (k >= N_TOT) return;
  int r, c;
  if (k < N_EDGES) { r = ei[k]; c = ei[N_EDGES + k]; } else { r = c = k - N_EDGES; }
  int pos = atomicAdd(&cursor[c], 1);
  srcs[pos] = r;
}

// ---------------- W-frag prep: W1,W2 fp32 -> bf16 B-frag layout in global ----------------
__global__ __launch_bounds__(256) void wfrag_kernel(const float* __restrict__ W1, const float* __restrict__ W2,
    unsigned short* __restrict__ wf1, unsigned short* __restrict__ wf2){
  int i = blockIdx.x*256 + threadIdx.x;   // 32768 threads exact
  if (i < 16384) {
    int k = i >> 8, n = i & 255;
    int kk = k >> 5, qq = (k >> 3) & 3, j = k & 7, nt = n >> 4, cc = n & 15;
    wf1[(((kk*16 + nt)*4 + qq)*16 + cc)*8 + j] = f2bu(W1[i]);
  } else {
    int i2 = i - 16384;
    int k = i2 >> 6, n = i2 & 63;
    int kk = k >> 5, qq = (k >> 3) & 3, j = k & 7, ch = n >> 4, cc = n & 15;
    wf2[(((kk*4 + ch)*4 + qq)*16 + cc)*8 + j] = f2bu(W2[i2]);
  }
}

// ---------------- GEMM1 (MFMA): h1pre = x @ W1  [50000,64]x[64,256] bf16, fused al1 ----------------
// 64-node tile / block, 4 waves; wave w owns n-tiles w*4..w*4+3. B-frags register-resident from wf1.
__global__ __launch_bounds__(256) void gemm1_kernel(const float* __restrict__ x, const unsigned short* __restrict__ wf1,
    const float* __restrict__ a1s, const float* __restrict__ a1d,
    bf16* __restrict__ h1pre, float* __restrict__ al1s, float* __restrict__ al1d){
  __shared__ __align__(16) unsigned short ctile[32*264];       // half-tile bf16, 16.5KB
  int tid = threadIdx.x, wave = tid >> 6, lane = tid & 63;
  int q = lane >> 4, c = lane & 15;
  int n0 = blockIdx.x * 64;

  union { uint4 u; bf16x8 v; } bfr[2][4];
  #pragma unroll
  for (int kk = 0; kk < 2; ++kk)
    #pragma unroll
    for (int nti = 0; nti < 4; ++nti)
      bfr[kk][nti].u = *(const uint4*)(wf1 + (size_t)((((kk*16 + wave*4 + nti)*4 + q)*16 + c)*8));

  float4 a1sv = *(const float4*)(a1s + lane*4);
  float4 a1dv = *(const float4*)(a1d + lane*4);

  #pragma unroll
  for (int half = 0; half < 2; ++half) {
    #pragma unroll
    for (int sti = 0; sti < 2; ++sti) {
      int st = half*2 + sti;
      int row = n0 + st*16 + c;
      if (row >= N_NODES) row = N_NODES - 1;   // tail clamp; stores guarded below
      bf16x8 afr[2];
      #pragma unroll
      for (int kk = 0; kk < 2; ++kk) {
        const float* xp = x + (size_t)row*64 + kk*32 + q*8;
        afr[kk] = pack8(*(const float4*)xp, *(const float4*)(xp + 4));
      }
      #pragma unroll
      for (int nti = 0; nti < 4; ++nti) {
        f32x4 acc = {0.f, 0.f, 0.f, 0.f};
        #pragma unroll
        for (int kk = 0; kk < 2; ++kk)
          acc = __builtin_amdgcn_mfma_f32_16x16x32_bf16(afr[kk], bfr[kk][nti].v, acc, 0, 0, 0);
        int lrow = sti*16 + q*4, nt = wave*4 + nti;
        #pragma unroll
        for (int r = 0; r < 4; ++r)
          ctile[(lrow + r)*264 + nt*16 + c] = f2bu(acc[r]);
      }
    }
    __syncthreads();
    // store phase: wave w -> local rows w*8..w*8+7; coalesced 512B/row + al1 reductions
    #pragma unroll 1
    for (int i = 0; i < 8; ++i) {
      int lr = wave*8 + i;
      int node = n0 + half*32 + lr;
      if (node < N_NODES) {
        uint2 dd = *(const uint2*)&ctile[lr*264 + lane*4];
        ((uint2*)h1pre)[(size_t)node*64 + lane] = dd;
        float v0 = bflo(dd.x), v1 = bfhi(dd.x), v2 = bflo(dd.y), v3 = bfhi(dd.y);
        float ps = v0*a1sv.x + v1*a1sv.y + v2*a1sv.z + v3*a1sv.w;
        float pd = v0*a1dv.x + v1*a1dv.y + v2*a1dv.z + v3*a1dv.w;
        #pragma unroll
        for (int off = 1; off < 16; off <<= 1) { ps += __shfl_xor(ps, off, 64); pd += __shfl_xor(pd, off, 64); }
        if ((lane & 15) == 0) {
          al1s[node*4 + (lane >> 4)] = ps;
          al1d[node*4 + (lane >> 4)] = pd;
        }
      }
    }
    __syncthreads();   // ctile reads done before next half's MFMA writes
  }
}

// ------- Attention layer 1 (H=4,C=64): wave per node; no max pass (softmax shift-invariant,
// |e| <= ~6 here so exp is safe in fp32); single gather pass stages p=exp(e).
// Aggregation: uint4/lane, 32 lanes cover a 512B row -> 2 edges per load instr, unroll 4
// => 8 rows (4KB) in flight per wave (vs 2 before), half the load instrs, coalesced uint4 store.
__global__ __launch_bounds__(256) void attn1_kernel(const bf16* __restrict__ h1pre,
    const float* __restrict__ al1s, const float* __restrict__ al1d,
    const int* __restrict__ offs, const int* __restrict__ srcs,
    const float* __restrict__ b1, bf16* __restrict__ h1){
  __shared__ __align__(16) float ebuf[4][MAXD][4];       // 8KB: p values
  __shared__ int sbuf[4][MAXD];                          // 2KB

  int wave = threadIdx.x >> 6, lane = threadIdx.x & 63;
  int n = blockIdx.x*4 + wave;          // 50000 % 4 == 0: no tail
  int start = offs[n], end = offs[n+1];
  int deg = end - start;
  float4 aldv = *(const float4*)(al1d + (size_t)n*4);
  float ald0 = aldv.x, ald1 = aldv.y, ald2 = aldv.z, ald3 = aldv.w;

  // single pass: gather als, e=lrelu, p=exp(e); stage p+src; lane sums
  float s0 = 0.f, s1 = 0.f, s2 = 0.f, s3 = 0.f;
  {
    int idx = lane;
    for (int j = start + lane; j < end; j += 64, idx += 64) {
      int r = srcs[j];
      float4 als = *(const float4*)(al1s + (size_t)r*4);
      float e0 = als.x + ald0; e0 = e0 >= 0.f ? e0 : 0.2f*e0; float p0 = __expf(e0); s0 += p0;
      float e1 = als.y + ald1; e1 = e1 >= 0.f ? e1 : 0.2f*e1; float p1 = __expf(e1); s1 += p1;
      float e2 = als.z + ald2; e2 = e2 >= 0.f ? e2 : 0.2f*e2; float p2 = __expf(e2); s2 += p2;
      float e3 = als.w + ald3; e3 = e3 >= 0.f ? e3 : 0.2f*e3; float p3 = __expf(e3); s3 += p3;
      if (idx < MAXD) {
        sbuf[wave][idx] = r;
        *(float4*)&ebuf[wave][idx][0] = make_float4(p0, p1, p2, p3);
      }
    }
  }
  #pragma unroll
  for (int off = 32; off; off >>= 1) {
    s0 += __shfl_xor(s0, off, 64);
    s1 += __shfl_xor(s1, off, 64);
    s2 += __shfl_xor(s2, off, 64);
    s3 += __shfl_xor(s3, off, 64);
  }
  float inv0 = 1.f/(s0 + 1e-16f), inv1 = 1.f/(s1 + 1e-16f);
  float inv2 = 1.f/(s2 + 1e-16f), inv3 = 1.f/(s3 + 1e-16f);

  // aggregation: lane -> (edge-slot es=lane>>5, channel-lane cl=lane&31); head h=cl>>3.
  // each lane: uint4 = 16B = channels cl*8 .. cl*8+7 of one row; 2 edges per iteration.
  int cl = lane & 31, es = lane >> 5, h = cl >> 3;
  float acc0 = 0.f, acc1 = 0.f, acc2 = 0.f, acc3 = 0.f;
  float acc4 = 0.f, acc5 = 0.f, acc6 = 0.f, acc7 = 0.f;
  {
    int lim = deg < MAXD ? deg : MAXD;
    const uint4* base4 = (const uint4*)h1pre;  // row = 32 uint4
    #pragma unroll 4
    for (int jj = 0; jj < lim; jj += 2) {
      int idx = jj + es;
      bool ok = idx < lim;
      int idxs = ok ? idx : 0;
      int r = sbuf[wave][idxs];
      float p = ok ? ebuf[wave][idxs][h] : 0.f;
      uint4 d = base4[(size_t)r*32 + cl];
      acc0 = fmaf(p, bflo(d.x), acc0);
      acc1 = fmaf(p, bfhi(d.x), acc1);
      acc2 = fmaf(p, bflo(d.y), acc2);
      acc3 = fmaf(p, bfhi(d.y), acc3);
      acc4 = fmaf(p, bflo(d.z), acc4);
      acc5 = fmaf(p, bfhi(d.z), acc5);
      acc6 = fmaf(p, bflo(d.w), acc6);
      acc7 = fmaf(p, bfhi(d.w), acc7);
    }
    if (deg > MAXD) {       // rare overflow tail
      float aldh = (h==0)?ald0:(h==1)?ald1:(h==2)?ald2:ald3;
      for (int jj = MAXD; jj < deg; jj += 2) {
        int idx = jj + es;
        bool ok = idx < deg;
        int j = ok ? (start + idx) : start;
        int r = srcs[j];
        float e = al1s[(size_t)r*4 + h] + aldh; e = e >= 0.f ? e : 0.2f*e;
        float p = ok ? __expf(e) : 0.f;
        uint4 d = base4[(size_t)r*32 + cl];
        acc0 = fmaf(p, bflo(d.x), acc0);
        acc1 = fmaf(p, bfhi(d.x), acc1);
        acc2 = fmaf(p, bflo(d.y), acc2);
        acc3 = fmaf(p, bfhi(d.y), acc3);
        acc4 = fmaf(p, bflo(d.z), acc4);
        acc5 = fmaf(p, bfhi(d.z), acc5);
        acc6 = fmaf(p, bflo(d.w), acc6);
        acc7 = fmaf(p, bfhi(d.w), acc7);
      }
    }
  }
  // fold the two edge slots
  acc0 += __shfl_xor(acc0, 32, 64);
  acc1 += __shfl_xor(acc1, 32, 64);
  acc2 += __shfl_xor(acc2, 32, 64);
  acc3 += __shfl_xor(acc3, 32, 64);
  acc4 += __shfl_xor(acc4, 32, 64);
  acc5 += __shfl_xor(acc5, 32, 64);
  acc6 += __shfl_xor(acc6, 32, 64);
  acc7 += __shfl_xor(acc7, 32, 64);

  // h1 row (post-bias ELU) -> global bf16, coalesced uint4 per lane (512B/row)
  {
    float invh = (h==0)?inv0:(h==1)?inv1:(h==2)?inv2:inv3;
    float4 ba = *(const float4*)(b1 + cl*8);
    float4 bb = *(const float4*)(b1 + cl*8 + 4);
    float o0 = acc0*invh + ba.x; o0 = o0 > 0.f ? o0 : expm1f(o0);
    float o1 = acc1*invh + ba.y; o1 = o1 > 0.f ? o1 : expm1f(o1);
    float o2 = acc2*invh + ba.z; o2 = o2 > 0.f ? o2 : expm1f(o2);
    float o3 = acc3*invh + ba.w; o3 = o3 > 0.f ? o3 : expm1f(o3);
    float o4 = acc4*invh + bb.x; o4 = o4 > 0.f ? o4 : expm1f(o4);
    float o5 = acc5*invh + bb.y; o5 = o5 > 0.f ? o5 : expm1f(o5);
    float o6 = acc6*invh + bb.z; o6 = o6 > 0.f ? o6 : expm1f(o6);
    float o7 = acc7*invh + bb.w; o7 = o7 > 0.f ? o7 : expm1f(o7);
    uint4 dd;
    dd.x = (unsigned)f2bu(o0) | ((unsigned)f2bu(o1) << 16);
    dd.y = (unsigned)f2bu(o2) | ((unsigned)f2bu(o3) << 16);
    dd.z = (unsigned)f2bu(o4) | ((unsigned)f2bu(o5) << 16);
    dd.w = (unsigned)f2bu(o6) | ((unsigned)f2bu(o7) << 16);
    if (es == 0) ((uint4*)h1)[(size_t)n*32 + cl] = dd;
  }
}

// ---------------- GEMM2 (MFMA): h2pre = h1 @ W2  [50000,256]bf16 x [256,64], fused al2 ----------------
__global__ __launch_bounds__(256) void gemm2_kernel(const bf16* __restrict__ h1, const unsigned short* __restrict__ wf2,
    const float* __restrict__ a2s, const float* __restrict__ a2d,
    bf16* __restrict__ h2pre, float* __restrict__ al2s, float* __restrict__ al2d){
  __shared__ __align__(16) float ctile[64][65];               // padded
  int tid = threadIdx.x, wave = tid >> 6, lane = tid & 63;
  int q = lane >> 4, c = lane & 15;
  int n0 = blockIdx.x * 64;

  union { uint4 u; bf16x8 v; } bfr[8];
  #pragma unroll
  for (int kk = 0; kk < 8; ++kk)
    bfr[kk].u = *(const uint4*)(wf2 + (size_t)((((kk*4 + wave)*4 + q)*16 + c)*8));

  const unsigned short* h1u = (const unsigned short*)h1;
  #pragma unroll 1
  for (int st = 0; st < 4; ++st) {
    if (n0 + st*16 >= N_NODES) break;
    f32x4 acc = {0.f, 0.f, 0.f, 0.f};
    size_t arow = (size_t)(n0 + st*16 + c)*256 + q*8;
    #pragma unroll
    for (int kk = 0; kk < 8; ++kk) {
      union { uint4 u; bf16x8 v; } a;
      a.u = *(const uint4*)(h1u + arow + kk*32);
      acc = __builtin_amdgcn_mfma_f32_16x16x32_bf16(a.v, bfr[kk].v, acc, 0, 0, 0);
    }
    #pragma unroll
    for (int r = 0; r < 4; ++r)
      ctile[st*16 + q*4 + r][wave*16 + c] = acc[r];
  }
  __syncthreads();

  float as = a2s[lane], ad = a2d[lane];
  #pragma unroll 1
  for (int i = 0; i < 16; ++i) {
    int node = n0 + wave*16 + i;
    if (node >= N_NODES) break;
    float val = ctile[wave*16 + i][lane];
    ((unsigned short*)h2pre)[(size_t)node*64 + lane] = f2bu(val);
    float ps = val*as, pd = val*ad;
    #pragma unroll
    for (int off = 32; off; off >>= 1) { ps += __shfl_xor(ps, off, 64); pd += __shfl_xor(pd, off, 64); }
    if (lane == 0) { al2s[node] = ps; al2d[node] = pd; }
  }
}

// ---------------- Attention layer 2 (H=1, no max pass) + node head + u/v; 8 waves/block ----------------
// Aggregation: uint4/lane, 8 lanes cover a 128B row -> 8 edges per load instr, unroll 2
// => 16 rows in flight per wave (avg degree 17 issues in ~1 pass).
__global__ __launch_bounds__(512) void attn2_kernel(const bf16* __restrict__ h2pre,
    const float* __restrict__ al2s, const float* __restrict__ al2d,
    const int* __restrict__ offs, const int* __restrict__ srcs,
    const float* __restrict__ b2, const float* __restrict__ Wn, const float* __restrict__ bn,
    const float* __restrict__ We,
    float* __restrict__ u, float* __restrict__ v, float* __restrict__ node_out){
  __shared__ float ebuf[8][MAXD];               // 4KB: p values
  __shared__ int   sbuf[8][MAXD];               // 4KB
  __shared__ __align__(16) float sh[8][64];     // 2KB
  int wave = threadIdx.x >> 6, lane = threadIdx.x & 63;
  int n = blockIdx.x*8 + wave;        // exact
  int start = offs[n], end = offs[n+1];
  int deg = end - start;
  float ald = al2d[n];

  float sm = 0.f;
  {
    int idx = lane;
    for (int j = start + lane; j < end; j += 64, idx += 64) {
      int r = srcs[j];
      float t = al2s[r] + ald; t = t >= 0.f ? t : 0.2f*t;
      float p = __expf(t); sm += p;
      if (idx < MAXD) { sbuf[wave][idx] = r; ebuf[wave][idx] = p; }
    }
  }
  #pragma unroll
  for (int off = 32; off; off >>= 1) sm += __shfl_xor(sm, off, 64);
  float inv = 1.f/(sm + 1e-16f);

  // aggregation: lane -> (edge-slot es=lane>>3, channel-lane cl=lane&7); uint4 = channels cl*8..cl*8+7
  int cl = lane & 7, es = lane >> 3;
  float acc0 = 0.f, acc1 = 0.f, acc2 = 0.f, acc3 = 0.f;
  float acc4 = 0.f, acc5 = 0.f, acc6 = 0.f, acc7 = 0.f;
  {
    int lim = deg < MAXD ? deg : MAXD;
    const uint4* base4 = (const uint4*)h2pre;   // row = 8 uint4
    #pragma unroll 2
    for (int jj = 0; jj < lim; jj += 8) {
      int idx = jj + es;
      bool ok = idx < lim;
      int idxs = ok ? idx : 0;
      int r = sbuf[wave][idxs];
      float p = ok ? ebuf[wave][idxs] : 0.f;
      uint4 d = base4[(size_t)r*8 + cl];
      acc0 = fmaf(p, bflo(d.x), acc0);
      acc1 = fmaf(p, bfhi(d.x), acc1);
      acc2 = fmaf(p, bflo(d.y), acc2);
      acc3 = fmaf(p, bfhi(d.y), acc3);
      acc4 = fmaf(p, bflo(d.z), acc4);
      acc5 = fmaf(p, bfhi(d.z), acc5);
      acc6 = fmaf(p, bflo(d.w), acc6);
      acc7 = fmaf(p, bfhi(d.w), acc7);
    }
    if (deg > MAXD) {     // rare overflow tail
      for (int jj = MAXD; jj < deg; jj += 8) {
        int idx = jj + es;
        bool ok = idx < deg;
        int j = ok ? (start + idx) : start;
        int r = srcs[j];
        float t = al2s[r] + ald; t = t >= 0.f ? t : 0.2f*t;
        float p = ok ? __expf(t) : 0.f;
        uint4 d = base4[(size_t)r*8 + cl];
        acc0 = fmaf(p, bflo(d.x), acc0);
        acc1 = fmaf(p, bfhi(d.x), acc1);
        acc2 = fmaf(p, bflo(d.y), acc2);
        acc3 = fmaf(p, bfhi(d.y), acc3);
        acc4 = fmaf(p, bflo(d.z), acc4);
        acc5 = fmaf(p, bfhi(d.z), acc5);
        acc6 = fmaf(p, bflo(d.w), acc6);
        acc7 = fmaf(p, bfhi(d.w), acc7);
      }
    }
  }
  // fold the 8 edge-slots (xor butterfly over lane bits 3,4,5); all lanes end with channel sums
  #pragma unroll
  for (int off = 8; off < 64; off <<= 1) {
    acc0 += __shfl_xor(acc0, off, 64);
    acc1 += __shfl_xor(acc1, off, 64);
    acc2 += __shfl_xor(acc2, off, 64);
    acc3 += __shfl_xor(acc3, off, 64);
    acc4 += __shfl_xor(acc4, off, 64);
    acc5 += __shfl_xor(acc5, off, 64);
    acc6 += __shfl_xor(acc6, off, 64);
    acc7 += __shfl_xor(acc7, off, 64);
  }

  float4 b2a = *(const float4*)(b2 + cl*8);
  float4 b2b = *(const float4*)(b2 + cl*8 + 4);
  float o0 = acc0*inv + b2a.x; o0 = o0 > 0.f ? o0 : expm1f(o0);
  float o1 = acc1*inv + b2a.y; o1 = o1 > 0.f ? o1 : expm1f(o1);
  float o2 = acc2*inv + b2a.z; o2 = o2 > 0.f ? o2 : expm1f(o2);
  float o3 = acc3*inv + b2a.w; o3 = o3 > 0.f ? o3 : expm1f(o3);
  float o4 = acc4*inv + b2b.x; o4 = o4 > 0.f ? o4 : expm1f(o4);
  float o5 = acc5*inv + b2b.y; o5 = o5 > 0.f ? o5 : expm1f(o5);
  float o6 = acc6*inv + b2b.z; o6 = o6 > 0.f ? o6 : expm1f(o6);
  float o7 = acc7*inv + b2b.w; o7 = o7 > 0.f ? o7 : expm1f(o7);

  // u[n] = h2 . We[0:64], v[n] = h2 . We[64:128]; lanes 0..7 hold distinct channel groups
  float4 wea = *(const float4*)(We + cl*8);
  float4 web = *(const float4*)(We + cl*8 + 4);
  float4 wva = *(const float4*)(We + 64 + cl*8);
  float4 wvb = *(const float4*)(We + 64 + cl*8 + 4);
  float pu = o0*wea.x + o1*wea.y + o2*wea.z + o3*wea.w
           + o4*web.x + o5*web.y + o6*web.z + o7*web.w;
  float pv = o0*wva.x + o1*wva.y + o2*wva.z + o3*wva.w
           + o4*wvb.x + o5*wvb.y + o6*wvb.z + o7*wvb.w;
  #pragma unroll
  for (int off = 1; off < 8; off <<= 1) { pu += __shfl_xor(pu, off, 64); pv += __shfl_xor(pv, off, 64); }
  if (lane == 0) { u[n] = pu; v[n] = pv; }

  if (es == 0) {
    *(float4*)&sh[wave][cl*8]     = make_float4(o0, o1, o2, o3);
    *(float4*)&sh[wave][cl*8 + 4] = make_float4(o4, o5, o6, o7);
  }
  __syncthreads();

  // node_out = h2 @ Wn + bn  (Wn: [64,32]); lanes split k-range in halves
  int jcol = lane & 31, half = lane >> 5;
  float a2 = 0.f;
  #pragma unroll 8
  for (int k2 = 0; k2 < 32; k2++) {
    int k = half*32 + k2;
    a2 = fmaf(sh[wave][k], Wn[k*32 + jcol], a2);
  }
  a2 += __shfl_xor(a2, 32, 64);
  if (lane < 32) node_out[(size_t)n*32 + lane] = a2 + bn[jcol];
}

// ---------------- Edge head: out = u[row] + v[col] + edge_attr . We[128:144] + be ----------------
__global__ __launch_bounds__(256) void edge_kernel(const int* __restrict__ ei, const float* __restrict__ ea,
    const float* __restrict__ u, const float* __restrict__ v,
    const float* __restrict__ We, const float* __restrict__ be, float* __restrict__ out){
  int k = blockIdx.x*256 + threadIdx.x;   // grid is exact: 800000/256
  int r = ei[k], c = ei[N_EDGES + k];
  float val = u[r] + v[c] + be[0];
  const float4* wp = (const float4*)(We + 128);
  const float4* p  = (const float4*)(ea + (size_t)k*16);
  #pragma unroll
  for (int jj = 0; jj < 4; jj++) {
    float4 q = p[jj], wq = wp[jj];
    val = fmaf(q.x, wq.x, val);
    val = fmaf(q.y, wq.y, val);
    val = fmaf(q.z, wq.z, val);
    val = fmaf(q.w, wq.w, val);
  }
  out[k] = val;
}

extern "C" void kernel_launch(void* const* d_in, const int* in_sizes, int n_in,
                              void* d_out, int out_size, void* d_ws, size_t ws_size,
                              hipStream_t stream) {
  const float* x   = (const float*)d_in[0];
  const int*   ei  = (const int*)d_in[1];
  const float* ea  = (const float*)d_in[2];
  const float* W1  = (const float*)d_in[3];
  const float* a1s = (const float*)d_in[4];
  const float* a1d = (const float*)d_in[5];
  const float* b1  = (const float*)d_in[6];
  const float* W2  = (const float*)d_in[7];
  const float* a2s = (const float*)d_in[8];
  const float* a2d = (const float*)d_in[9];
  const float* b2  = (const float*)d_in[10];
  const float* Wn  = (const float*)d_in[11];
  const float* bn  = (const float*)d_in[12];
  const float* We  = (const float*)d_in[13];
  const float* be  = (const float*)d_in[14];
  float* out = (float*)d_out;

  // ---- workspace layout, peak 64,000,224 B (proven OK r7-r9), 16B-aligned ----
  char* w = (char*)d_ws;
  int*   offs   = (int*)(w);                        //       0 .. 200,016
  int*   cnt    = (int*)(w + 200016);               // 200,016 .. 400,016 (wf1 aliases after scans)
  int*   cursor = (int*)(w + 400016);               // 400,016 .. 600,016 (wf2 aliases after scatter)
  int*   srcs   = (int*)(w + 600016);               // 600,016 .. 4,000,016
  float* al1s   = (float*)(w + 4000016);            // [N,4] fp32, .. 4,800,016
  float* al1d   = (float*)(w + 4800016);            // [N,4] fp32, .. 5,600,016
  float* al2s   = (float*)(w + 5600016);            // [N] fp32,  .. 5,800,016
  float* al2d   = (float*)(w + 5800016);            // .. 6,000,016
  float* uu     = (float*)(w + 6000016);            // .. 6,200,016
  float* vv     = (float*)(w + 6200016);            // .. 6,400,016
  bf16*  h2pre  = (bf16*)(w + 6400016);             // [N,64] bf16, .. 12,800,016
  bf16*  h1pre  = (bf16*)(w + 12800016);            // [N,256] bf16, .. 38,400,016
  int*   psum   = (int*)(w + 38400016);             // 49 partials .. 38,400,212
  bf16*  h1     = (bf16*)(w + 38400224);            // [N,256] bf16, .. 64,000,224
  unsigned short* wf1 = (unsigned short*)cnt;       // 32,768 B  (cnt dead after scanC)
  unsigned short* wf2 = (unsigned short*)cursor;    // 32,768 B  (cursor dead after scatter)

  const int NPART = (N_NODES + 1023) / 1024;        // 49

  hipMemsetAsync(cnt, 0, (size_t)N_NODES * 4, stream);
  hist_kernel   <<<(N_TOT + 255)/256, 256, 0, stream>>>(ei, cnt);
  scanA_kernel  <<<NPART, 1024, 0, stream>>>(cnt, psum);
  scanB_kernel  <<<1, 64, 0, stream>>>(psum, NPART);
  scanC_kernel  <<<NPART, 1024, 0, stream>>>(cnt, psum, offs, cursor);
  scatter_kernel<<<(N_TOT + 255)/256, 256, 0, stream>>>(ei, cursor, srcs);
  wfrag_kernel  <<<128, 256, 0, stream>>>(W1, W2, wf1, wf2);
  gemm1_kernel  <<<(N_NODES + 63)/64, 256, 0, stream>>>(x, wf1, a1s, a1d, h1pre, al1s, al1d);
  attn1_kernel  <<<N_NODES/4, 256, 0, stream>>>(h1pre, al1s, al1d, offs, srcs, b1, h1);
  gemm2_kernel  <<<(N_NODES + 63)/64, 256, 0, stream>>>(h1, wf2, a2s, a2d, h2pre, al2s, al2d);
  attn2_kernel  <<<N_NODES/8, 512, 0, stream>>>(h2pre, al2s, al2d, offs, srcs, b2, Wn, bn, We,
                                                uu, vv, out);
  edge_kernel   <<<N_EDGES/256, 256, 0, stream>>>(ei, ea, uu, vv, We, be, out + (size_t)N_NODES*32);
}

// Round 2
// 373.103 us; speedup vs baseline: 1.0792x; 1.0568x over previous
//
#include <hip/hip_runtime.h>
#include <hip/hip_bf16.h>

#define N_NODES 50000
#define N_EDGES 800000
#define N_TOT   850000   // edges + self loops
#define MAXD    128      // LDS-staged edges per node; tail handled by fallback

typedef __hip_bfloat16 bf16;
typedef __attribute__((ext_vector_type(8))) short bf16x8;   // MFMA A/B frag (4 VGPRs)
typedef __attribute__((ext_vector_type(4))) float f32x4;    // MFMA C/D frag

__device__ __forceinline__ unsigned short f2bu(float v){
  union { bf16 b; unsigned short u; } cv; cv.b = __float2bfloat16(v); return cv.u;
}
__device__ __forceinline__ float bflo(unsigned int d){ return __uint_as_float(d << 16); }
__device__ __forceinline__ float bfhi(unsigned int d){ return __uint_as_float(d & 0xffff0000u); }

// ---------------- CSR build (group edges by destination = col) ----------------
__global__ __launch_bounds__(256) void hist_kernel(const int* __restrict__ ei, int* __restrict__ cnt){
  int k = blockIdx.x*256 + threadIdx.x;
  if (k >= N_TOT) return;
  int c = (k < N_EDGES) ? ei[N_EDGES + k] : (k - N_EDGES);
  atomicAdd(&cnt[c], 1);
}

// hierarchical scan: A) per-1024-block sums  B) scan 49 partials  C) per-block scan + base
__global__ __launch_bounds__(1024) void scanA_kernel(const int* __restrict__ cnt, int* __restrict__ psum){
  __shared__ int wsum[16];
  int tid = threadIdx.x, i = blockIdx.x*1024 + tid;
  int v = (i < N_NODES) ? cnt[i] : 0;
  #pragma unroll
  for (int off = 32; off; off >>= 1) v += __shfl_xor(v, off, 64);
  if ((tid & 63) == 0) wsum[tid >> 6] = v;
  __syncthreads();
  if (tid < 64) {
    int t = (tid < 16) ? wsum[tid] : 0;
    #pragma unroll
    for (int off = 8; off; off >>= 1) t += __shfl_xor(t, off, 64);
    if (tid == 0) psum[blockIdx.x] = t;
  }
}

__global__ __launch_bounds__(64) void scanB_kernel(int* __restrict__ psum, int nparts){
  int lane = threadIdx.x;
  int v = (lane < nparts) ? psum[lane] : 0;
  #pragma unroll
  for (int off = 1; off < 64; off <<= 1) {
    int t = __shfl_up(v, off, 64);
    if (lane >= off) v += t;
  }
  int e = __shfl_up(v, 1, 64);
  if (lane == 0) e = 0;
  if (lane < nparts) psum[lane] = e;
}

__global__ __launch_bounds__(1024) void scanC_kernel(const int* __restrict__ cnt, const int* __restrict__ psum,
                                                     int* __restrict__ offs, int* __restrict__ cursor){
  __shared__ int sm[1024];
  int tid = threadIdx.x, b = blockIdx.x, i = b*1024 + tid;
  int v = (i < N_NODES) ? cnt[i] : 0;
  sm[tid] = v;
  __syncthreads();
  for (int off = 1; off < 1024; off <<= 1) {
    int t = (tid >= off) ? sm[tid - off] : 0;
    __syncthreads();
    sm[tid] += t;
    __syncthreads();
  }
  if (i < N_NODES) {
    int e = psum[b] + sm[tid] - v;
    offs[i] = e; cursor[i] = e;
  }
  if (b == 0 && tid == 0) offs[N_NODES] = N_TOT;
}

__global__ __launch_bounds__(256) void scatter_kernel(const int* __restrict__ ei,
                                                      int* __restrict__ cursor,
                                                      int* __restrict__ srcs){
  int k = blockIdx.x*256 + threadIdx.x;
  if (k >= N_TOT) return;
  int r, c;
  if (k < N_EDGES) { r = ei[k]; c = ei[N_EDGES + k]; } else { r = c = k - N_EDGES; }
  int pos = atomicAdd(&cursor[c], 1);
  srcs[pos] = r;
}

// ---------------- W-frag prep + attention-vector fold ----------------
// blocks 0..127: W1,W2 fp32 -> bf16 B-frag layout.  block 128: ws1/wd1 = per-head W1 . a1{s,d}
__global__ __launch_bounds__(256) void wfrag_kernel(const float* __restrict__ W1, const float* __restrict__ W2,
    const float* __restrict__ a1s, const float* __restrict__ a1d,
    unsigned short* __restrict__ wf1, unsigned short* __restrict__ wf2,
    float* __restrict__ ws1, float* __restrict__ wd1){
  int b = blockIdx.x, tid = threadIdx.x;
  if (b < 128) {
    int i = b*256 + tid;   // 32768 threads exact
    if (i < 16384) {
      int k = i >> 8, n = i & 255;
      int kk = k >> 5, qq = (k >> 3) & 3, j = k & 7, nt = n >> 4, cc = n & 15;
      wf1[(((kk*16 + nt)*4 + qq)*16 + cc)*8 + j] = f2bu(W1[i]);
    } else {
      int i2 = i - 16384;
      int k = i2 >> 6, n = i2 & 63;
      int kk = k >> 5, qq = (k >> 3) & 3, j = k & 7, ch = n >> 4, cc = n & 15;
      wf2[(((kk*4 + ch)*4 + qq)*16 + cc)*8 + j] = f2bu(W2[i2]);
    }
  } else {
    // ws1[k][h] = sum_c W1[k, h*64+c] * a1s[h, c]   (64x4 each)
    int k = tid >> 2, h = tid & 3;
    const float* wrow = W1 + k*256 + h*64;
    const float* as = a1s + h*64;
    const float* ad = a1d + h*64;
    float ss = 0.f, sd = 0.f;
    #pragma unroll 8
    for (int c = 0; c < 64; ++c) {
      float wv = wrow[c];
      ss = fmaf(wv, as[c], ss);
      sd = fmaf(wv, ad[c], sd);
    }
    ws1[k*4 + h] = ss;
    wd1[k*4 + h] = sd;
  }
}

// ---------------- xprep: xb = bf16(x); al1{s,d} = x @ w{s,d}1  (fp32, more accurate than via h1pre) ----
// 16 nodes/block: 16-lane group per node, lane g covers ch g*4..g*4+3
__global__ __launch_bounds__(256) void xprep_kernel(const float* __restrict__ x,
    const float* __restrict__ ws1, const float* __restrict__ wd1,
    unsigned short* __restrict__ xb, float* __restrict__ al1s, float* __restrict__ al1d){
  __shared__ float sws[64][4], swd[64][4];
  int tid = threadIdx.x;
  sws[tid >> 2][tid & 3] = ws1[tid];
  swd[tid >> 2][tid & 3] = wd1[tid];
  __syncthreads();
  int lane = tid & 63, wave = tid >> 6;
  int g = lane & 15, sub = lane >> 4;
  int n = blockIdx.x*16 + wave*4 + sub;     // 50000/16 = 3125 exact
  float4 xv = *(const float4*)(x + (size_t)n*64 + g*4);
  uint2 dd;
  dd.x = (unsigned)f2bu(xv.x) | ((unsigned)f2bu(xv.y) << 16);
  dd.y = (unsigned)f2bu(xv.z) | ((unsigned)f2bu(xv.w) << 16);
  ((uint2*)xb)[(size_t)n*16 + g] = dd;
  int c0 = g*4;
  float ps0 = 0.f, ps1 = 0.f, ps2 = 0.f, ps3 = 0.f;
  float pd0 = 0.f, pd1 = 0.f, pd2 = 0.f, pd3 = 0.f;
  float xc[4] = {xv.x, xv.y, xv.z, xv.w};
  #pragma unroll
  for (int i = 0; i < 4; ++i) {
    int c = c0 + i;
    ps0 = fmaf(xc[i], sws[c][0], ps0); ps1 = fmaf(xc[i], sws[c][1], ps1);
    ps2 = fmaf(xc[i], sws[c][2], ps2); ps3 = fmaf(xc[i], sws[c][3], ps3);
    pd0 = fmaf(xc[i], swd[c][0], pd0); pd1 = fmaf(xc[i], swd[c][1], pd1);
    pd2 = fmaf(xc[i], swd[c][2], pd2); pd3 = fmaf(xc[i], swd[c][3], pd3);
  }
  #pragma unroll
  for (int off = 1; off < 16; off <<= 1) {
    ps0 += __shfl_xor(ps0, off, 64); ps1 += __shfl_xor(ps1, off, 64);
    ps2 += __shfl_xor(ps2, off, 64); ps3 += __shfl_xor(ps3, off, 64);
    pd0 += __shfl_xor(pd0, off, 64); pd1 += __shfl_xor(pd1, off, 64);
    pd2 += __shfl_xor(pd2, off, 64); pd3 += __shfl_xor(pd3, off, 64);
  }
  if (g < 4)      al1s[(size_t)n*4 + g]       = (g==0)?ps0:(g==1)?ps1:(g==2)?ps2:ps3;
  else if (g < 8) al1d[(size_t)n*4 + (g-4)]   = (g==4)?pd0:(g==5)?pd1:(g==6)?pd2:pd3;
}

// ------- Attention layer 1 in x-space: ag[n,h,:64] = sum_j alpha_{j,h} * xb[r_j]
// gather table = xb (6.4MB, 128B rows -> L2-resident). 16 lanes/row (uint2), 4 edge slots.
__global__ __launch_bounds__(256) void attn1x_kernel(const unsigned short* __restrict__ xb,
    const float* __restrict__ al1s, const float* __restrict__ al1d,
    const int* __restrict__ offs, const int* __restrict__ srcs,
    bf16* __restrict__ ag){
  __shared__ __align__(16) float ebuf[4][MAXD][4];       // 8KB: p values
  __shared__ int sbuf[4][MAXD];                          // 2KB

  int wave = threadIdx.x >> 6, lane = threadIdx.x & 63;
  int n = blockIdx.x*4 + wave;          // 50000 % 4 == 0: no tail
  int start = offs[n], end = offs[n+1];
  int deg = end - start;
  float4 aldv = *(const float4*)(al1d + (size_t)n*4);
  float ald0 = aldv.x, ald1 = aldv.y, ald2 = aldv.z, ald3 = aldv.w;

  // stage pass: gather als, e=lrelu, p=exp(e); stage p+src; lane sums
  float s0 = 0.f, s1 = 0.f, s2 = 0.f, s3 = 0.f;
  {
    int idx = lane;
    for (int j = start + lane; j < end; j += 64, idx += 64) {
      int r = srcs[j];
      float4 als = *(const float4*)(al1s + (size_t)r*4);
      float e0 = als.x + ald0; e0 = e0 >= 0.f ? e0 : 0.2f*e0; float p0 = __expf(e0); s0 += p0;
      float e1 = als.y + ald1; e1 = e1 >= 0.f ? e1 : 0.2f*e1; float p1 = __expf(e1); s1 += p1;
      float e2 = als.z + ald2; e2 = e2 >= 0.f ? e2 : 0.2f*e2; float p2 = __expf(e2); s2 += p2;
      float e3 = als.w + ald3; e3 = e3 >= 0.f ? e3 : 0.2f*e3; float p3 = __expf(e3); s3 += p3;
      if (idx < MAXD) {
        sbuf[wave][idx] = r;
        *(float4*)&ebuf[wave][idx][0] = make_float4(p0, p1, p2, p3);
      }
    }
  }
  #pragma unroll
  for (int off = 32; off; off >>= 1) {
    s0 += __shfl_xor(s0, off, 64);
    s1 += __shfl_xor(s1, off, 64);
    s2 += __shfl_xor(s2, off, 64);
    s3 += __shfl_xor(s3, off, 64);
  }
  float inv0 = 1.f/(s0 + 1e-16f), inv1 = 1.f/(s1 + 1e-16f);
  float inv2 = 1.f/(s2 + 1e-16f), inv3 = 1.f/(s3 + 1e-16f);

  // aggregation: lane -> (edge-slot es=lane>>4 of 4, ch-lane cl=lane&15: ch cl*4..cl*4+3)
  // per iter: 4 edges; per lane: 1 uint2 row-load (8B), 4 unpack, 16 fma (4 heads x 4 ch)
  int cl = lane & 15, es = lane >> 4;
  float acc[4][4];
  #pragma unroll
  for (int h = 0; h < 4; ++h)
    #pragma unroll
    for (int i = 0; i < 4; ++i) acc[h][i] = 0.f;
  {
    int lim = deg < MAXD ? deg : MAXD;
    const uint2* base2 = (const uint2*)xb;   // row = 16 uint2 (128B)
    #pragma unroll 2
    for (int jj = 0; jj < lim; jj += 4) {
      int idx = jj + es;
      bool ok = idx < lim;
      int idxs = ok ? idx : 0;
      int r = sbuf[wave][idxs];
      float4 pv = *(const float4*)&ebuf[wave][idxs][0];
      float m = ok ? 1.f : 0.f;
      uint2 d = base2[(size_t)r*16 + cl];
      float c0 = bflo(d.x)*m, c1 = bfhi(d.x)*m, c2 = bflo(d.y)*m, c3 = bfhi(d.y)*m;
      acc[0][0] = fmaf(pv.x, c0, acc[0][0]); acc[0][1] = fmaf(pv.x, c1, acc[0][1]);
      acc[0][2] = fmaf(pv.x, c2, acc[0][2]); acc[0][3] = fmaf(pv.x, c3, acc[0][3]);
      acc[1][0] = fmaf(pv.y, c0, acc[1][0]); acc[1][1] = fmaf(pv.y, c1, acc[1][1]);
      acc[1][2] = fmaf(pv.y, c2, acc[1][2]); acc[1][3] = fmaf(pv.y, c3, acc[1][3]);
      acc[2][0] = fmaf(pv.z, c0, acc[2][0]); acc[2][1] = fmaf(pv.z, c1, acc[2][1]);
      acc[2][2] = fmaf(pv.z, c2, acc[2][2]); acc[2][3] = fmaf(pv.z, c3, acc[2][3]);
      acc[3][0] = fmaf(pv.w, c0, acc[3][0]); acc[3][1] = fmaf(pv.w, c1, acc[3][1]);
      acc[3][2] = fmaf(pv.w, c2, acc[3][2]); acc[3][3] = fmaf(pv.w, c3, acc[3][3]);
    }
    if (deg > MAXD) {       // rare overflow tail: recompute p per lane
      for (int jj = MAXD; jj < deg; jj += 4) {
        int idx = jj + es;
        bool ok = idx < deg;
        int j = ok ? (start + idx) : start;
        int r = srcs[j];
        float4 als = *(const float4*)(al1s + (size_t)r*4);
        float e0 = als.x + ald0; e0 = e0 >= 0.f ? e0 : 0.2f*e0; float p0 = __expf(e0);
        float e1 = als.y + ald1; e1 = e1 >= 0.f ? e1 : 0.2f*e1; float p1 = __expf(e1);
        float e2 = als.z + ald2; e2 = e2 >= 0.f ? e2 : 0.2f*e2; float p2 = __expf(e2);
        float e3 = als.w + ald3; e3 = e3 >= 0.f ? e3 : 0.2f*e3; float p3 = __expf(e3);
        float m = ok ? 1.f : 0.f;
        uint2 d = base2[(size_t)r*16 + cl];
        float c0 = bflo(d.x)*m, c1 = bfhi(d.x)*m, c2 = bflo(d.y)*m, c3 = bfhi(d.y)*m;
        acc[0][0] = fmaf(p0, c0, acc[0][0]); acc[0][1] = fmaf(p0, c1, acc[0][1]);
        acc[0][2] = fmaf(p0, c2, acc[0][2]); acc[0][3] = fmaf(p0, c3, acc[0][3]);
        acc[1][0] = fmaf(p1, c0, acc[1][0]); acc[1][1] = fmaf(p1, c1, acc[1][1]);
        acc[1][2] = fmaf(p1, c2, acc[1][2]); acc[1][3] = fmaf(p1, c3, acc[1][3]);
        acc[2][0] = fmaf(p2, c0, acc[2][0]); acc[2][1] = fmaf(p2, c1, acc[2][1]);
        acc[2][2] = fmaf(p2, c2, acc[2][2]); acc[2][3] = fmaf(p2, c3, acc[2][3]);
        acc[3][0] = fmaf(p3, c0, acc[3][0]); acc[3][1] = fmaf(p3, c1, acc[3][1]);
        acc[3][2] = fmaf(p3, c2, acc[3][2]); acc[3][3] = fmaf(p3, c3, acc[3][3]);
      }
    }
  }
  // fold the 4 edge slots (lane bits 4,5); afterwards every lane holds full sums for its cl
  #pragma unroll
  for (int h = 0; h < 4; ++h)
    #pragma unroll
    for (int i = 0; i < 4; ++i) {
      acc[h][i] += __shfl_xor(acc[h][i], 16, 64);
      acc[h][i] += __shfl_xor(acc[h][i], 32, 64);
    }
  // lane l writes head h=es, channels cl*4..cl*4+3: ag[n][es*64 + cl*4 ...] (coalesced 512B/row)
  {
    float invh = (es==0)?inv0:(es==1)?inv1:(es==2)?inv2:inv3;
    float o0 = ((es==0)?acc[0][0]:(es==1)?acc[1][0]:(es==2)?acc[2][0]:acc[3][0]) * invh;
    float o1 = ((es==0)?acc[0][1]:(es==1)?acc[1][1]:(es==2)?acc[2][1]:acc[3][1]) * invh;
    float o2 = ((es==0)?acc[0][2]:(es==1)?acc[1][2]:(es==2)?acc[2][2]:acc[3][2]) * invh;
    float o3 = ((es==0)?acc[0][3]:(es==1)?acc[1][3]:(es==2)?acc[2][3]:acc[3][3]) * invh;
    uint2 dd;
    dd.x = (unsigned)f2bu(o0) | ((unsigned)f2bu(o1) << 16);
    dd.y = (unsigned)f2bu(o2) | ((unsigned)f2bu(o3) << 16);
    ((uint2*)ag)[(size_t)n*64 + lane] = dd;
  }
}

// ---------------- GEMM1b (MFMA, block-diagonal): h1[:, h*64:+64] = elu(ag[:,h,:] @ W1[:, h-block] + b1)
// wave w = head w; B-frags from wf1 (nt = w*4..w*4+3), A from ag rows (already bf16).
__global__ __launch_bounds__(256) void gemm1b_kernel(const unsigned short* __restrict__ ag,
    const unsigned short* __restrict__ wf1, const float* __restrict__ b1, bf16* __restrict__ h1){
  __shared__ __align__(16) unsigned short ctile[32*264];       // half-tile bf16, 16.5KB
  int tid = threadIdx.x, wave = tid >> 6, lane = tid & 63;
  int q = lane >> 4, c = lane & 15;
  int n0 = blockIdx.x * 64;

  union { uint4 u; bf16x8 v; } bfr[2][4];
  #pragma unroll
  for (int kk = 0; kk < 2; ++kk)
    #pragma unroll
    for (int nti = 0; nti < 4; ++nti)
      bfr[kk][nti].u = *(const uint4*)(wf1 + (size_t)((((kk*16 + wave*4 + nti)*4 + q)*16 + c)*8));

  float b1v[4];
  #pragma unroll
  for (int nti = 0; nti < 4; ++nti) b1v[nti] = b1[(wave*4 + nti)*16 + c];

  #pragma unroll
  for (int half = 0; half < 2; ++half) {
    #pragma unroll
    for (int sti = 0; sti < 2; ++sti) {
      int st = half*2 + sti;
      int row = n0 + st*16 + c;
      if (row >= N_NODES) row = N_NODES - 1;   // tail clamp; stores guarded below
      bf16x8 afr[2];
      #pragma unroll
      for (int kk = 0; kk < 2; ++kk) {
        union { uint4 u; bf16x8 v; } a;
        a.u = *(const uint4*)(ag + (size_t)row*256 + wave*64 + kk*32 + q*8);
        afr[kk] = a.v;
      }
      #pragma unroll
      for (int nti = 0; nti < 4; ++nti) {
        f32x4 acc = {0.f, 0.f, 0.f, 0.f};
        #pragma unroll
        for (int kk = 0; kk < 2; ++kk)
          acc = __builtin_amdgcn_mfma_f32_16x16x32_bf16(afr[kk], bfr[kk][nti].v, acc, 0, 0, 0);
        int lrow = sti*16 + q*4, nt = wave*4 + nti;
        #pragma unroll
        for (int r = 0; r < 4; ++r) {
          float o = acc[r] + b1v[nti];
          o = o > 0.f ? o : expm1f(o);
          ctile[(lrow + r)*264 + nt*16 + c] = f2bu(o);
        }
      }
    }
    __syncthreads();
    // store phase: wave w -> local rows w*8..w*8+7; coalesced 512B/row
    #pragma unroll 1
    for (int i = 0; i < 8; ++i) {
      int lr = wave*8 + i;
      int node = n0 + half*32 + lr;
      if (node < N_NODES) {
        uint2 dd = *(const uint2*)&ctile[lr*264 + lane*4];
        ((uint2*)h1)[(size_t)node*64 + lane] = dd;
      }
    }
    __syncthreads();
  }
}

// ---------------- GEMM2 (MFMA): h2pre = h1 @ W2  [50000,256]bf16 x [256,64], fused al2 ----------------
__global__ __launch_bounds__(256) void gemm2_kernel(const bf16* __restrict__ h1, const unsigned short* __restrict__ wf2,
    const float* __restrict__ a2s, const float* __restrict__ a2d,
    bf16* __restrict__ h2pre, float* __restrict__ al2s, float* __restrict__ al2d){
  __shared__ __align__(16) float ctile[64][65];               // padded
  int tid = threadIdx.x, wave = tid >> 6, lane = tid & 63;
  int q = lane >> 4, c = lane & 15;
  int n0 = blockIdx.x * 64;

  union { uint4 u; bf16x8 v; } bfr[8];
  #pragma unroll
  for (int kk = 0; kk < 8; ++kk)
    bfr[kk].u = *(const uint4*)(wf2 + (size_t)((((kk*4 + wave)*4 + q)*16 + c)*8));

  const unsigned short* h1u = (const unsigned short*)h1;
  #pragma unroll 1
  for (int st = 0; st < 4; ++st) {
    if (n0 + st*16 >= N_NODES) break;
    f32x4 acc = {0.f, 0.f, 0.f, 0.f};
    size_t arow = (size_t)(n0 + st*16 + c)*256 + q*8;
    #pragma unroll
    for (int kk = 0; kk < 8; ++kk) {
      union { uint4 u; bf16x8 v; } a;
      a.u = *(const uint4*)(h1u + arow + kk*32);
      acc = __builtin_amdgcn_mfma_f32_16x16x32_bf16(a.v, bfr[kk].v, acc, 0, 0, 0);
    }
    #pragma unroll
    for (int r = 0; r < 4; ++r)
      ctile[st*16 + q*4 + r][wave*16 + c] = acc[r];
  }
  __syncthreads();

  float as = a2s[lane], ad = a2d[lane];
  #pragma unroll 1
  for (int i = 0; i < 16; ++i) {
    int node = n0 + wave*16 + i;
    if (node >= N_NODES) break;
    float val = ctile[wave*16 + i][lane];
    ((unsigned short*)h2pre)[(size_t)node*64 + lane] = f2bu(val);
    float ps = val*as, pd = val*ad;
    #pragma unroll
    for (int off = 32; off; off >>= 1) { ps += __shfl_xor(ps, off, 64); pd += __shfl_xor(pd, off, 64); }
    if (lane == 0) { al2s[node] = ps; al2d[node] = pd; }
  }
}

// ---------------- Attention layer 2 (H=1, no max pass) + node head + u/v; 8 waves/block ----------------
__global__ __launch_bounds__(512) void attn2_kernel(const bf16* __restrict__ h2pre,
    const float* __restrict__ al2s, const float* __restrict__ al2d,
    const int* __restrict__ offs, const int* __restrict__ srcs,
    const float* __restrict__ b2, const float* __restrict__ Wn, const float* __restrict__ bn,
    const float* __restrict__ We,
    float* __restrict__ u, float* __restrict__ v, float* __restrict__ node_out){
  __shared__ float ebuf[8][MAXD];               // 4KB: p values
  __shared__ int   sbuf[8][MAXD];               // 4KB
  __shared__ __align__(16) float sh[8][64];     // 2KB
  int wave = threadIdx.x >> 6, lane = threadIdx.x & 63;
  int n = blockIdx.x*8 + wave;        // exact
  int start = offs[n], end = offs[n+1];
  int deg = end - start;
  float ald = al2d[n];

  float sm = 0.f;
  {
    int idx = lane;
    for (int j = start + lane; j < end; j += 64, idx += 64) {
      int r = srcs[j];
      float t = al2s[r] + ald; t = t >= 0.f ? t : 0.2f*t;
      float p = __expf(t); sm += p;
      if (idx < MAXD) { sbuf[wave][idx] = r; ebuf[wave][idx] = p; }
    }
  }
  #pragma unroll
  for (int off = 32; off; off >>= 1) sm += __shfl_xor(sm, off, 64);
  float inv = 1.f/(sm + 1e-16f);

  // aggregation: lane -> (edge-slot es=lane>>3, channel-lane cl=lane&7); uint4 = channels cl*8..cl*8+7
  int cl = lane & 7, es = lane >> 3;
  float acc0 = 0.f, acc1 = 0.f, acc2 = 0.f, acc3 = 0.f;
  float acc4 = 0.f, acc5 = 0.f, acc6 = 0.f, acc7 = 0.f;
  {
    int lim = deg < MAXD ? deg : MAXD;
    const uint4* base4 = (const uint4*)h2pre;   // row = 8 uint4
    #pragma unroll 2
    for (int jj = 0; jj < lim; jj += 8) {
      int idx = jj + es;
      bool ok = idx < lim;
      int idxs = ok ? idx : 0;
      int r = sbuf[wave][idxs];
      float p = ok ? ebuf[wave][idxs] : 0.f;
      uint4 d = base4[(size_t)r*8 + cl];
      acc0 = fmaf(p, bflo(d.x), acc0);
      acc1 = fmaf(p, bfhi(d.x), acc1);
      acc2 = fmaf(p, bflo(d.y), acc2);
      acc3 = fmaf(p, bfhi(d.y), acc3);
      acc4 = fmaf(p, bflo(d.z), acc4);
      acc5 = fmaf(p, bfhi(d.z), acc5);
      acc6 = fmaf(p, bflo(d.w), acc6);
      acc7 = fmaf(p, bfhi(d.w), acc7);
    }
    if (deg > MAXD) {     // rare overflow tail
      for (int jj = MAXD; jj < deg; jj += 8) {
        int idx = jj + es;
        bool ok = idx < deg;
        int j = ok ? (start + idx) : start;
        int r = srcs[j];
        float t = al2s[r] + ald; t = t >= 0.f ? t : 0.2f*t;
        float p = ok ? __expf(t) : 0.f;
        uint4 d = base4[(size_t)r*8 + cl];
        acc0 = fmaf(p, bflo(d.x), acc0);
        acc1 = fmaf(p, bfhi(d.x), acc1);
        acc2 = fmaf(p, bflo(d.y), acc2);
        acc3 = fmaf(p, bfhi(d.y), acc3);
        acc4 = fmaf(p, bflo(d.z), acc4);
        acc5 = fmaf(p, bfhi(d.z), acc5);
        acc6 = fmaf(p, bflo(d.w), acc6);
        acc7 = fmaf(p, bfhi(d.w), acc7);
      }
    }
  }
  // fold the 8 edge-slots (xor butterfly over lane bits 3,4,5); all lanes end with channel sums
  #pragma unroll
  for (int off = 8; off < 64; off <<= 1) {
    acc0 += __shfl_xor(acc0, off, 64);
    acc1 += __shfl_xor(acc1, off, 64);
    acc2 += __shfl_xor(acc2, off, 64);
    acc3 += __shfl_xor(acc3, off, 64);
    acc4 += __shfl_xor(acc4, off, 64);
    acc5 += __shfl_xor(acc5, off, 64);
    acc6 += __shfl_xor(acc6, off, 64);
    acc7 += __shfl_xor(acc7, off, 64);
  }

  float4 b2a = *(const float4*)(b2 + cl*8);
  float4 b2b = *(const float4*)(b2 + cl*8 + 4);
  float o0 = acc0*inv + b2a.x; o0 = o0 > 0.f ? o0 : expm1f(o0);
  float o1 = acc1*inv + b2a.y; o1 = o1 > 0.f ? o1 : expm1f(o1);
  float o2 = acc2*inv + b2a.z; o2 = o2 > 0.f ? o2 : expm1f(o2);
  float o3 = acc3*inv + b2a.w; o3 = o3 > 0.f ? o3 : expm1f(o3);
  float o4 = acc4*inv + b2b.x; o4 = o4 > 0.f ? o4 : expm1f(o4);
  float o5 = acc5*inv + b2b.y; o5 = o5 > 0.f ? o5 : expm1f(o5);
  float o6 = acc6*inv + b2b.z; o6 = o6 > 0.f ? o6 : expm1f(o6);
  float o7 = acc7*inv + b2b.w; o7 = o7 > 0.f ? o7 : expm1f(o7);

  // u[n] = h2 . We[0:64], v[n] = h2 . We[64:128]; lanes 0..7 hold distinct channel groups
  float4 wea = *(const float4*)(We + cl*8);
  float4 web = *(const float4*)(We + cl*8 + 4);
  float4 wva = *(const float4*)(We + 64 + cl*8);
  float4 wvb = *(const float4*)(We + 64 + cl*8 + 4);
  float pu = o0*wea.x + o1*wea.y + o2*wea.z + o3*wea.w
           + o4*web.x + o5*web.y + o6*web.z + o7*web.w;
  float pv = o0*wva.x + o1*wva.y + o2*wva.z + o3*wva.w
           + o4*wvb.x + o5*wvb.y + o6*wvb.z + o7*wvb.w;
  #pragma unroll
  for (int off = 1; off < 8; off <<= 1) { pu += __shfl_xor(pu, off, 64); pv += __shfl_xor(pv, off, 64); }
  if (lane == 0) { u[n] = pu; v[n] = pv; }

  if (es == 0) {
    *(float4*)&sh[wave][cl*8]     = make_float4(o0, o1, o2, o3);
    *(float4*)&sh[wave][cl*8 + 4] = make_float4(o4, o5, o6, o7);
  }
  __syncthreads();

  // node_out = h2 @ Wn + bn  (Wn: [64,32]); lanes split k-range in halves
  int jcol = lane & 31, half = lane >> 5;
  float a2 = 0.f;
  #pragma unroll 8
  for (int k2 = 0; k2 < 32; k2++) {
    int k = half*32 + k2;
    a2 = fmaf(sh[wave][k], Wn[k*32 + jcol], a2);
  }
  a2 += __shfl_xor(a2, 32, 64);
  if (lane < 32) node_out[(size_t)n*32 + lane] = a2 + bn[jcol];
}

// ---------------- Edge head: out = u[row] + v[col] + edge_attr . We[128:144] + be ----------------
__global__ __launch_bounds__(256) void edge_kernel(const int* __restrict__ ei, const float* __restrict__ ea,
    const float* __restrict__ u, const float* __restrict__ v,
    const float* __restrict__ We, const float* __restrict__ be, float* __restrict__ out){
  int k = blockIdx.x*256 + threadIdx.x;   // grid is exact: 800000/256
  int r = ei[k], c = ei[N_EDGES + k];
  float val = u[r] + v[c] + be[0];
  const float4* wp = (const float4*)(We + 128);
  const float4* p  = (const float4*)(ea + (size_t)k*16);
  #pragma unroll
  for (int jj = 0; jj < 4; jj++) {
    float4 q = p[jj], wq = wp[jj];
    val = fmaf(q.x, wq.x, val);
    val = fmaf(q.y, wq.y, val);
    val = fmaf(q.z, wq.z, val);
    val = fmaf(q.w, wq.w, val);
  }
  out[k] = val;
}

extern "C" void kernel_launch(void* const* d_in, const int* in_sizes, int n_in,
                              void* d_out, int out_size, void* d_ws, size_t ws_size,
                              hipStream_t stream) {
  const float* x   = (const float*)d_in[0];
  const int*   ei  = (const int*)d_in[1];
  const float* ea  = (const float*)d_in[2];
  const float* W1  = (const float*)d_in[3];
  const float* a1s = (const float*)d_in[4];
  const float* a1d = (const float*)d_in[5];
  const float* b1  = (const float*)d_in[6];
  const float* W2  = (const float*)d_in[7];
  const float* a2s = (const float*)d_in[8];
  const float* a2d = (const float*)d_in[9];
  const float* b2  = (const float*)d_in[10];
  const float* Wn  = (const float*)d_in[11];
  const float* bn  = (const float*)d_in[12];
  const float* We  = (const float*)d_in[13];
  const float* be  = (const float*)d_in[14];
  float* out = (float*)d_out;

  // ---- workspace layout, peak 64,000,224 B (unchanged), 16B-aligned ----
  char* w = (char*)d_ws;
  int*   offs   = (int*)(w);                        //       0 .. 200,016
  int*   cnt    = (int*)(w + 200016);               // 200,016 .. 400,016 (wf1/ws1/wd1 alias after scans)
  int*   cursor = (int*)(w + 400016);               // 400,016 .. 600,016 (wf2 aliases after scatter)
  int*   srcs   = (int*)(w + 600016);               // 600,016 .. 4,000,016
  float* al1s   = (float*)(w + 4000016);            // [N,4] fp32, .. 4,800,016
  float* al1d   = (float*)(w + 4800016);            // [N,4] fp32, .. 5,600,016
  float* al2s   = (float*)(w + 5600016);            // [N] fp32,  .. 5,800,016
  float* al2d   = (float*)(w + 5800016);            // .. 6,000,016
  float* uu     = (float*)(w + 6000016);            // .. 6,200,016
  float* vv     = (float*)(w + 6200016);            // .. 6,400,016
  bf16*  h2pre  = (bf16*)(w + 6400016);             // [N,64] bf16, .. 12,800,016 (xb aliases BEFORE gemm2)
  bf16*  ag     = (bf16*)(w + 12800016);            // [N,256] bf16 aggregate, .. 38,400,016
  int*   psum   = (int*)(w + 38400016);             // 49 partials .. 38,400,212
  bf16*  h1     = (bf16*)(w + 38400224);            // [N,256] bf16, .. 64,000,224
  unsigned short* wf1 = (unsigned short*)cnt;       // 32,768 B  (cnt dead after scanC)
  float* ws1 = (float*)(w + 232784);                // 1KB, inside cnt region after wf1
  float* wd1 = (float*)(w + 233808);                // 1KB
  unsigned short* wf2 = (unsigned short*)cursor;    // 32,768 B  (cursor dead after scatter)
  unsigned short* xb  = (unsigned short*)h2pre;     // [N,64] bf16 x-table; dead before gemm2 writes h2pre

  const int NPART = (N_NODES + 1023) / 1024;        // 49

  hipMemsetAsync(cnt, 0, (size_t)N_NODES * 4, stream);
  hist_kernel   <<<(N_TOT + 255)/256, 256, 0, stream>>>(ei, cnt);
  scanA_kernel  <<<NPART, 1024, 0, stream>>>(cnt, psum);
  scanB_kernel  <<<1, 64, 0, stream>>>(psum, NPART);
  scanC_kernel  <<<NPART, 1024, 0, stream>>>(cnt, psum, offs, cursor);
  scatter_kernel<<<(N_TOT + 255)/256, 256, 0, stream>>>(ei, cursor, srcs);
  wfrag_kernel  <<<129, 256, 0, stream>>>(W1, W2, a1s, a1d, wf1, wf2, ws1, wd1);
  xprep_kernel  <<<N_NODES/16, 256, 0, stream>>>(x, ws1, wd1, xb, al1s, al1d);
  attn1x_kernel <<<N_NODES/4, 256, 0, stream>>>(xb, al1s, al1d, offs, srcs, ag);
  gemm1b_kernel <<<(N_NODES + 63)/64, 256, 0, stream>>>((const unsigned short*)ag, wf1, b1, h1);
  gemm2_kernel  <<<(N_NODES + 63)/64, 256, 0, stream>>>(h1, wf2, a2s, a2d, h2pre, al2s, al2d);
  attn2_kernel  <<<N_NODES/8, 512, 0, stream>>>(h2pre, al2s, al2d, offs, srcs, b2, Wn, bn, We,
                                                uu, vv, out);
  edge_kernel   <<<N_EDGES/256, 256, 0, stream>>>(ei, ea, uu, vv, We, be, out + (size_t)N_NODES*32);
}

// Round 3
// 317.040 us; speedup vs baseline: 1.2701x; 1.1768x over previous
//
#include <hip/hip_runtime.h>
#include <hip/hip_bf16.h>

#define N_NODES 50000
#define N_EDGES 800000
#define N_TOT   850000   // edges + self loops
#define MAXD    128      // LDS-staged edges per node; tail handled by fallback

// bucketed CSR build: bucket = dst >> 8 (256 nodes/bucket)
#define NBUCK 196        // ceil(50000/256)
#define BCAP  8192       // fixed bucket capacity (mean 4337, std ~66 -> 58 sigma slack)

typedef __hip_bfloat16 bf16;
typedef __attribute__((ext_vector_type(8))) short bf16x8;   // MFMA A/B frag (4 VGPRs)
typedef __attribute__((ext_vector_type(4))) float f32x4;    // MFMA C/D frag

__device__ __forceinline__ unsigned short f2bu(float v){
  union { bf16 b; unsigned short u; } cv; cv.b = __float2bfloat16(v); return cv.u;
}
__device__ __forceinline__ float bflo(unsigned int d){ return __uint_as_float(d << 16); }
__device__ __forceinline__ float bfhi(unsigned int d){ return __uint_as_float(d & 0xffff0000u); }

// ---------------- CSR build, stage 0: bucket cursors ----------------
__global__ __launch_bounds__(256) void initb_kernel(int* __restrict__ bcur){
  int i = threadIdx.x;
  if (i < NBUCK) bcur[i] = i * BCAP;
}

// ---------------- CSR build, stage 1: bin edges into 196 bucket regions ----------------
// block = 256 thr x 16 edges = 4096 edges; LDS hist -> one global atomic per bucket per block;
// packed entry = (dst&255)<<16 | src  (src<50000 fits 16 bits)
__global__ __launch_bounds__(256) void binscatter_kernel(const int* __restrict__ ei,
    int* __restrict__ bcur, unsigned int* __restrict__ pairbuf){
  __shared__ int hist[NBUCK];
  __shared__ int gbase[NBUCK];
  int tid = threadIdx.x;
  if (tid < NBUCK) hist[tid] = 0;
  __syncthreads();
  int base = blockIdx.x * 4096;
  #pragma unroll 4
  for (int i = 0; i < 16; ++i) {
    int k = base + i*256 + tid;
    if (k < N_TOT) {
      int c = (k < N_EDGES) ? ei[N_EDGES + k] : (k - N_EDGES);
      atomicAdd(&hist[c >> 8], 1);
    }
  }
  __syncthreads();
  if (tid < NBUCK) {
    int h = hist[tid];
    gbase[tid] = h ? atomicAdd(&bcur[tid], h) : 0;
    hist[tid] = 0;                       // reuse as local cursor
  }
  __syncthreads();
  #pragma unroll 4
  for (int i = 0; i < 16; ++i) {
    int k = base + i*256 + tid;
    if (k < N_TOT) {
      int r, c;
      if (k < N_EDGES) { r = ei[k]; c = ei[N_EDGES + k]; } else { r = c = k - N_EDGES; }
      int b = c >> 8;
      int lpos = atomicAdd(&hist[b], 1);
      pairbuf[gbase[b] + lpos] = (unsigned)r | ((unsigned)(c & 255) << 16);
    }
  }
}

// ---------------- CSR build, stage 2: per-bucket node counts (no global atomics) ----------------
__global__ __launch_bounds__(256) void bcount_kernel(const unsigned int* __restrict__ pairbuf,
    const int* __restrict__ bcur, int* __restrict__ cnt){
  __shared__ int lhist[256];
  int b = blockIdx.x, tid = threadIdx.x;
  lhist[tid] = 0;
  __syncthreads();
  int base = b * BCAP;
  int size = bcur[b] - base; if (size > BCAP) size = BCAP;
  for (int j = tid; j < size; j += 256)
    atomicAdd(&lhist[pairbuf[base + j] >> 16], 1);
  __syncthreads();
  int node = b*256 + tid;
  if (node < N_NODES) cnt[node] = lhist[tid];
}

// hierarchical scan: A) per-1024-block sums  B) scan 49 partials  C) per-block scan + base
__global__ __launch_bounds__(1024) void scanA_kernel(const int* __restrict__ cnt, int* __restrict__ psum){
  __shared__ int wsum[16];
  int tid = threadIdx.x, i = blockIdx.x*1024 + tid;
  int v = (i < N_NODES) ? cnt[i] : 0;
  #pragma unroll
  for (int off = 32; off; off >>= 1) v += __shfl_xor(v, off, 64);
  if ((tid & 63) == 0) wsum[tid >> 6] = v;
  __syncthreads();
  if (tid < 64) {
    int t = (tid < 16) ? wsum[tid] : 0;
    #pragma unroll
    for (int off = 8; off; off >>= 1) t += __shfl_xor(t, off, 64);
    if (tid == 0) psum[blockIdx.x] = t;
  }
}

__global__ __launch_bounds__(64) void scanB_kernel(int* __restrict__ psum, int nparts){
  int lane = threadIdx.x;
  int v = (lane < nparts) ? psum[lane] : 0;
  #pragma unroll
  for (int off = 1; off < 64; off <<= 1) {
    int t = __shfl_up(v, off, 64);
    if (lane >= off) v += t;
  }
  int e = __shfl_up(v, 1, 64);
  if (lane == 0) e = 0;
  if (lane < nparts) psum[lane] = e;
}

__global__ __launch_bounds__(1024) void scanC_kernel(const int* __restrict__ cnt, const int* __restrict__ psum,
                                                     int* __restrict__ offs){
  __shared__ int sm[1024];
  int tid = threadIdx.x, b = blockIdx.x, i = b*1024 + tid;
  int v = (i < N_NODES) ? cnt[i] : 0;
  sm[tid] = v;
  __syncthreads();
  for (int off = 1; off < 1024; off <<= 1) {
    int t = (tid >= off) ? sm[tid - off] : 0;
    __syncthreads();
    sm[tid] += t;
    __syncthreads();
  }
  if (i < N_NODES) offs[i] = psum[b] + sm[tid] - v;
  if (b == 0 && tid == 0) offs[N_NODES] = N_TOT;
}

// ---------------- CSR build, stage 3: per-bucket local scatter into contiguous srcs span ----------------
__global__ __launch_bounds__(256) void lscatter_kernel(const unsigned int* __restrict__ pairbuf,
    const int* __restrict__ bcur, const int* __restrict__ offs, int* __restrict__ srcs){
  __shared__ int lcur[256];
  int b = blockIdx.x, tid = threadIdx.x;
  int lo = b*256;
  if (lo + tid < N_NODES) lcur[tid] = offs[lo + tid];
  __syncthreads();
  int base = b * BCAP;
  int size = bcur[b] - base; if (size > BCAP) size = BCAP;
  for (int j = tid; j < size; j += 256) {
    unsigned v = pairbuf[base + j];
    int pos = atomicAdd(&lcur[v >> 16], 1);
    srcs[pos] = (int)(v & 0xFFFFu);
  }
}

// ---------------- W-frag prep + attention-vector fold ----------------
// blocks 0..127: W1,W2 fp32 -> bf16 B-frag layout.  block 128: ws1/wd1 = per-head W1 . a1{s,d}
__global__ __launch_bounds__(256) void wfrag_kernel(const float* __restrict__ W1, const float* __restrict__ W2,
    const float* __restrict__ a1s, const float* __restrict__ a1d,
    unsigned short* __restrict__ wf1, unsigned short* __restrict__ wf2,
    float* __restrict__ ws1, float* __restrict__ wd1){
  int b = blockIdx.x, tid = threadIdx.x;
  if (b < 128) {
    int i = b*256 + tid;   // 32768 threads exact
    if (i < 16384) {
      int k = i >> 8, n = i & 255;
      int kk = k >> 5, qq = (k >> 3) & 3, j = k & 7, nt = n >> 4, cc = n & 15;
      wf1[(((kk*16 + nt)*4 + qq)*16 + cc)*8 + j] = f2bu(W1[i]);
    } else {
      int i2 = i - 16384;
      int k = i2 >> 6, n = i2 & 63;
      int kk = k >> 5, qq = (k >> 3) & 3, j = k & 7, ch = n >> 4, cc = n & 15;
      wf2[(((kk*4 + ch)*4 + qq)*16 + cc)*8 + j] = f2bu(W2[i2]);
    }
  } else {
    // ws1[k][h] = sum_c W1[k, h*64+c] * a1s[h, c]   (64x4 each)
    int k = tid >> 2, h = tid & 3;
    const float* wrow = W1 + k*256 + h*64;
    const float* as = a1s + h*64;
    const float* ad = a1d + h*64;
    float ss = 0.f, sd = 0.f;
    #pragma unroll 8
    for (int c = 0; c < 64; ++c) {
      float wv = wrow[c];
      ss = fmaf(wv, as[c], ss);
      sd = fmaf(wv, ad[c], sd);
    }
    ws1[k*4 + h] = ss;
    wd1[k*4 + h] = sd;
  }
}

// ---------------- xprep: xb = bf16(x); al1{s,d} = x @ w{s,d}1  (fp32, more accurate than via h1pre) ----
// 16 nodes/block: 16-lane group per node, lane g covers ch g*4..g*4+3
__global__ __launch_bounds__(256) void xprep_kernel(const float* __restrict__ x,
    const float* __restrict__ ws1, const float* __restrict__ wd1,
    unsigned short* __restrict__ xb, float* __restrict__ al1s, float* __restrict__ al1d){
  __shared__ float sws[64][4], swd[64][4];
  int tid = threadIdx.x;
  sws[tid >> 2][tid & 3] = ws1[tid];
  swd[tid >> 2][tid & 3] = wd1[tid];
  __syncthreads();
  int lane = tid & 63, wave = tid >> 6;
  int g = lane & 15, sub = lane >> 4;
  int n = blockIdx.x*16 + wave*4 + sub;     // 50000/16 = 3125 exact
  float4 xv = *(const float4*)(x + (size_t)n*64 + g*4);
  uint2 dd;
  dd.x = (unsigned)f2bu(xv.x) | ((unsigned)f2bu(xv.y) << 16);
  dd.y = (unsigned)f2bu(xv.z) | ((unsigned)f2bu(xv.w) << 16);
  ((uint2*)xb)[(size_t)n*16 + g] = dd;
  int c0 = g*4;
  float ps0 = 0.f, ps1 = 0.f, ps2 = 0.f, ps3 = 0.f;
  float pd0 = 0.f, pd1 = 0.f, pd2 = 0.f, pd3 = 0.f;
  float xc[4] = {xv.x, xv.y, xv.z, xv.w};
  #pragma unroll
  for (int i = 0; i < 4; ++i) {
    int c = c0 + i;
    ps0 = fmaf(xc[i], sws[c][0], ps0); ps1 = fmaf(xc[i], sws[c][1], ps1);
    ps2 = fmaf(xc[i], sws[c][2], ps2); ps3 = fmaf(xc[i], sws[c][3], ps3);
    pd0 = fmaf(xc[i], swd[c][0], pd0); pd1 = fmaf(xc[i], swd[c][1], pd1);
    pd2 = fmaf(xc[i], swd[c][2], pd2); pd3 = fmaf(xc[i], swd[c][3], pd3);
  }
  #pragma unroll
  for (int off = 1; off < 16; off <<= 1) {
    ps0 += __shfl_xor(ps0, off, 64); ps1 += __shfl_xor(ps1, off, 64);
    ps2 += __shfl_xor(ps2, off, 64); ps3 += __shfl_xor(ps3, off, 64);
    pd0 += __shfl_xor(pd0, off, 64); pd1 += __shfl_xor(pd1, off, 64);
    pd2 += __shfl_xor(pd2, off, 64); pd3 += __shfl_xor(pd3, off, 64);
  }
  if (g < 4)      al1s[(size_t)n*4 + g]       = (g==0)?ps0:(g==1)?ps1:(g==2)?ps2:ps3;
  else if (g < 8) al1d[(size_t)n*4 + (g-4)]   = (g==4)?pd0:(g==5)?pd1:(g==6)?pd2:pd3;
}

// ------- Attention layer 1 in x-space: ag[n,h,:64] = sum_j alpha_{j,h} * xb[r_j]
// gather table = xb (6.4MB, 128B rows -> L2-resident). 16 lanes/row (uint2), 4 edge slots.
__global__ __launch_bounds__(256) void attn1x_kernel(const unsigned short* __restrict__ xb,
    const float* __restrict__ al1s, const float* __restrict__ al1d,
    const int* __restrict__ offs, const int* __restrict__ srcs,
    bf16* __restrict__ ag){
  __shared__ __align__(16) float ebuf[4][MAXD][4];       // 8KB: p values
  __shared__ int sbuf[4][MAXD];                          // 2KB

  int wave = threadIdx.x >> 6, lane = threadIdx.x & 63;
  int n = blockIdx.x*4 + wave;          // 50000 % 4 == 0: no tail
  int start = offs[n], end = offs[n+1];
  int deg = end - start;
  float4 aldv = *(const float4*)(al1d + (size_t)n*4);
  float ald0 = aldv.x, ald1 = aldv.y, ald2 = aldv.z, ald3 = aldv.w;

  // stage pass: gather als, e=lrelu, p=exp(e); stage p+src; lane sums
  float s0 = 0.f, s1 = 0.f, s2 = 0.f, s3 = 0.f;
  {
    int idx = lane;
    for (int j = start + lane; j < end; j += 64, idx += 64) {
      int r = srcs[j];
      float4 als = *(const float4*)(al1s + (size_t)r*4);
      float e0 = als.x + ald0; e0 = e0 >= 0.f ? e0 : 0.2f*e0; float p0 = __expf(e0); s0 += p0;
      float e1 = als.y + ald1; e1 = e1 >= 0.f ? e1 : 0.2f*e1; float p1 = __expf(e1); s1 += p1;
      float e2 = als.z + ald2; e2 = e2 >= 0.f ? e2 : 0.2f*e2; float p2 = __expf(e2); s2 += p2;
      float e3 = als.w + ald3; e3 = e3 >= 0.f ? e3 : 0.2f*e3; float p3 = __expf(e3); s3 += p3;
      if (idx < MAXD) {
        sbuf[wave][idx] = r;
        *(float4*)&ebuf[wave][idx][0] = make_float4(p0, p1, p2, p3);
      }
    }
  }
  #pragma unroll
  for (int off = 32; off; off >>= 1) {
    s0 += __shfl_xor(s0, off, 64);
    s1 += __shfl_xor(s1, off, 64);
    s2 += __shfl_xor(s2, off, 64);
    s3 += __shfl_xor(s3, off, 64);
  }
  float inv0 = 1.f/(s0 + 1e-16f), inv1 = 1.f/(s1 + 1e-16f);
  float inv2 = 1.f/(s2 + 1e-16f), inv3 = 1.f/(s3 + 1e-16f);

  // aggregation: lane -> (edge-slot es=lane>>4 of 4, ch-lane cl=lane&15: ch cl*4..cl*4+3)
  // per iter: 4 edges; per lane: 1 uint2 row-load (8B), 4 unpack, 16 fma (4 heads x 4 ch)
  int cl = lane & 15, es = lane >> 4;
  float acc[4][4];
  #pragma unroll
  for (int h = 0; h < 4; ++h)
    #pragma unroll
    for (int i = 0; i < 4; ++i) acc[h][i] = 0.f;
  {
    int lim = deg < MAXD ? deg : MAXD;
    const uint2* base2 = (const uint2*)xb;   // row = 16 uint2 (128B)
    #pragma unroll 2
    for (int jj = 0; jj < lim; jj += 4) {
      int idx = jj + es;
      bool ok = idx < lim;
      int idxs = ok ? idx : 0;
      int r = sbuf[wave][idxs];
      float4 pv = *(const float4*)&ebuf[wave][idxs][0];
      float m = ok ? 1.f : 0.f;
      uint2 d = base2[(size_t)r*16 + cl];
      float c0 = bflo(d.x)*m, c1 = bfhi(d.x)*m, c2 = bflo(d.y)*m, c3 = bfhi(d.y)*m;
      acc[0][0] = fmaf(pv.x, c0, acc[0][0]); acc[0][1] = fmaf(pv.x, c1, acc[0][1]);
      acc[0][2] = fmaf(pv.x, c2, acc[0][2]); acc[0][3] = fmaf(pv.x, c3, acc[0][3]);
      acc[1][0] = fmaf(pv.y, c0, acc[1][0]); acc[1][1] = fmaf(pv.y, c1, acc[1][1]);
      acc[1][2] = fmaf(pv.y, c2, acc[1][2]); acc[1][3] = fmaf(pv.y, c3, acc[1][3]);
      acc[2][0] = fmaf(pv.z, c0, acc[2][0]); acc[2][1] = fmaf(pv.z, c1, acc[2][1]);
      acc[2][2] = fmaf(pv.z, c2, acc[2][2]); acc[2][3] = fmaf(pv.z, c3, acc[2][3]);
      acc[3][0] = fmaf(pv.w, c0, acc[3][0]); acc[3][1] = fmaf(pv.w, c1, acc[3][1]);
      acc[3][2] = fmaf(pv.w, c2, acc[3][2]); acc[3][3] = fmaf(pv.w, c3, acc[3][3]);
    }
    if (deg > MAXD) {       // rare overflow tail: recompute p per lane
      for (int jj = MAXD; jj < deg; jj += 4) {
        int idx = jj + es;
        bool ok = idx < deg;
        int j = ok ? (start + idx) : start;
        int r = srcs[j];
        float4 als = *(const float4*)(al1s + (size_t)r*4);
        float e0 = als.x + ald0; e0 = e0 >= 0.f ? e0 : 0.2f*e0; float p0 = __expf(e0);
        float e1 = als.y + ald1; e1 = e1 >= 0.f ? e1 : 0.2f*e1; float p1 = __expf(e1);
        float e2 = als.z + ald2; e2 = e2 >= 0.f ? e2 : 0.2f*e2; float p2 = __expf(e2);
        float e3 = als.w + ald3; e3 = e3 >= 0.f ? e3 : 0.2f*e3; float p3 = __expf(e3);
        float m = ok ? 1.f : 0.f;
        uint2 d = base2[(size_t)r*16 + cl];
        float c0 = bflo(d.x)*m, c1 = bfhi(d.x)*m, c2 = bflo(d.y)*m, c3 = bfhi(d.y)*m;
        acc[0][0] = fmaf(p0, c0, acc[0][0]); acc[0][1] = fmaf(p0, c1, acc[0][1]);
        acc[0][2] = fmaf(p0, c2, acc[0][2]); acc[0][3] = fmaf(p0, c3, acc[0][3]);
        acc[1][0] = fmaf(p1, c0, acc[1][0]); acc[1][1] = fmaf(p1, c1, acc[1][1]);
        acc[1][2] = fmaf(p1, c2, acc[1][2]); acc[1][3] = fmaf(p1, c3, acc[1][3]);
        acc[2][0] = fmaf(p2, c0, acc[2][0]); acc[2][1] = fmaf(p2, c1, acc[2][1]);
        acc[2][2] = fmaf(p2, c2, acc[2][2]); acc[2][3] = fmaf(p2, c3, acc[2][3]);
        acc[3][0] = fmaf(p3, c0, acc[3][0]); acc[3][1] = fmaf(p3, c1, acc[3][1]);
        acc[3][2] = fmaf(p3, c2, acc[3][2]); acc[3][3] = fmaf(p3, c3, acc[3][3]);
      }
    }
  }
  // fold the 4 edge slots (lane bits 4,5); afterwards every lane holds full sums for its cl
  #pragma unroll
  for (int h = 0; h < 4; ++h)
    #pragma unroll
    for (int i = 0; i < 4; ++i) {
      acc[h][i] += __shfl_xor(acc[h][i], 16, 64);
      acc[h][i] += __shfl_xor(acc[h][i], 32, 64);
    }
  // lane l writes head h=es, channels cl*4..cl*4+3: ag[n][es*64 + cl*4 ...] (coalesced 512B/row)
  {
    float invh = (es==0)?inv0:(es==1)?inv1:(es==2)?inv2:inv3;
    float o0 = ((es==0)?acc[0][0]:(es==1)?acc[1][0]:(es==2)?acc[2][0]:acc[3][0]) * invh;
    float o1 = ((es==0)?acc[0][1]:(es==1)?acc[1][1]:(es==2)?acc[2][1]:acc[3][1]) * invh;
    float o2 = ((es==0)?acc[0][2]:(es==1)?acc[1][2]:(es==2)?acc[2][2]:acc[3][2]) * invh;
    float o3 = ((es==0)?acc[0][3]:(es==1)?acc[1][3]:(es==2)?acc[2][3]:acc[3][3]) * invh;
    uint2 dd;
    dd.x = (unsigned)f2bu(o0) | ((unsigned)f2bu(o1) << 16);
    dd.y = (unsigned)f2bu(o2) | ((unsigned)f2bu(o3) << 16);
    ((uint2*)ag)[(size_t)n*64 + lane] = dd;
  }
}

// ---------------- GEMM1b (MFMA, block-diagonal): h1[:, h*64:+64] = elu(ag[:,h,:] @ W1[:, h-block] + b1)
// wave w = head w; B-frags from wf1 (nt = w*4..w*4+3), A from ag rows (already bf16).
__global__ __launch_bounds__(256) void gemm1b_kernel(const unsigned short* __restrict__ ag,
    const unsigned short* __restrict__ wf1, const float* __restrict__ b1, bf16* __restrict__ h1){
  __shared__ __align__(16) unsigned short ctile[32*264];       // half-tile bf16, 16.5KB
  int tid = threadIdx.x, wave = tid >> 6, lane = tid & 63;
  int q = lane >> 4, c = lane & 15;
  int n0 = blockIdx.x * 64;

  union { uint4 u; bf16x8 v; } bfr[2][4];
  #pragma unroll
  for (int kk = 0; kk < 2; ++kk)
    #pragma unroll
    for (int nti = 0; nti < 4; ++nti)
      bfr[kk][nti].u = *(const uint4*)(wf1 + (size_t)((((kk*16 + wave*4 + nti)*4 + q)*16 + c)*8));

  float b1v[4];
  #pragma unroll
  for (int nti = 0; nti < 4; ++nti) b1v[nti] = b1[(wave*4 + nti)*16 + c];

  #pragma unroll
  for (int half = 0; half < 2; ++half) {
    #pragma unroll
    for (int sti = 0; sti < 2; ++sti) {
      int st = half*2 + sti;
      int row = n0 + st*16 + c;
      if (row >= N_NODES) row = N_NODES - 1;   // tail clamp; stores guarded below
      bf16x8 afr[2];
      #pragma unroll
      for (int kk = 0; kk < 2; ++kk) {
        union { uint4 u; bf16x8 v; } a;
        a.u = *(const uint4*)(ag + (size_t)row*256 + wave*64 + kk*32 + q*8);
        afr[kk] = a.v;
      }
      #pragma unroll
      for (int nti = 0; nti < 4; ++nti) {
        f32x4 acc = {0.f, 0.f, 0.f, 0.f};
        #pragma unroll
        for (int kk = 0; kk < 2; ++kk)
          acc = __builtin_amdgcn_mfma_f32_16x16x32_bf16(afr[kk], bfr[kk][nti].v, acc, 0, 0, 0);
        int lrow = sti*16 + q*4, nt = wave*4 + nti;
        #pragma unroll
        for (int r = 0; r < 4; ++r) {
          float o = acc[r] + b1v[nti];
          o = o > 0.f ? o : expm1f(o);
          ctile[(lrow + r)*264 + nt*16 + c] = f2bu(o);
        }
      }
    }
    __syncthreads();
    // store phase: wave w -> local rows w*8..w*8+7; coalesced 512B/row
    #pragma unroll 1
    for (int i = 0; i < 8; ++i) {
      int lr = wave*8 + i;
      int node = n0 + half*32 + lr;
      if (node < N_NODES) {
        uint2 dd = *(const uint2*)&ctile[lr*264 + lane*4];
        ((uint2*)h1)[(size_t)node*64 + lane] = dd;
      }
    }
    __syncthreads();
  }
}

// ---------------- GEMM2 (MFMA): h2pre = h1 @ W2  [50000,256]bf16 x [256,64], fused al2 ----------------
__global__ __launch_bounds__(256) void gemm2_kernel(const bf16* __restrict__ h1, const unsigned short* __restrict__ wf2,
    const float* __restrict__ a2s, const float* __restrict__ a2d,
    bf16* __restrict__ h2pre, float* __restrict__ al2s, float* __restrict__ al2d){
  __shared__ __align__(16) float ctile[64][65];               // padded
  int tid = threadIdx.x, wave = tid >> 6, lane = tid & 63;
  int q = lane >> 4, c = lane & 15;
  int n0 = blockIdx.x * 64;

  union { uint4 u; bf16x8 v; } bfr[8];
  #pragma unroll
  for (int kk = 0; kk < 8; ++kk)
    bfr[kk].u = *(const uint4*)(wf2 + (size_t)((((kk*4 + wave)*4 + q)*16 + c)*8));

  const unsigned short* h1u = (const unsigned short*)h1;
  #pragma unroll 1
  for (int st = 0; st < 4; ++st) {
    if (n0 + st*16 >= N_NODES) break;
    f32x4 acc = {0.f, 0.f, 0.f, 0.f};
    size_t arow = (size_t)(n0 + st*16 + c)*256 + q*8;
    #pragma unroll
    for (int kk = 0; kk < 8; ++kk) {
      union { uint4 u; bf16x8 v; } a;
      a.u = *(const uint4*)(h1u + arow + kk*32);
      acc = __builtin_amdgcn_mfma_f32_16x16x32_bf16(a.v, bfr[kk].v, acc, 0, 0, 0);
    }
    #pragma unroll
    for (int r = 0; r < 4; ++r)
      ctile[st*16 + q*4 + r][wave*16 + c] = acc[r];
  }
  __syncthreads();

  float as = a2s[lane], ad = a2d[lane];
  #pragma unroll 1
  for (int i = 0; i < 16; ++i) {
    int node = n0 + wave*16 + i;
    if (node >= N_NODES) break;
    float val = ctile[wave*16 + i][lane];
    ((unsigned short*)h2pre)[(size_t)node*64 + lane] = f2bu(val);
    float ps = val*as, pd = val*ad;
    #pragma unroll
    for (int off = 32; off; off >>= 1) { ps += __shfl_xor(ps, off, 64); pd += __shfl_xor(pd, off, 64); }
    if (lane == 0) { al2s[node] = ps; al2d[node] = pd; }
  }
}

// ---------------- Attention layer 2 (H=1, no max pass) + node head + u/v; 8 waves/block ----------------
__global__ __launch_bounds__(512) void attn2_kernel(const bf16* __restrict__ h2pre,
    const float* __restrict__ al2s, const float* __restrict__ al2d,
    const int* __restrict__ offs, const int* __restrict__ srcs,
    const float* __restrict__ b2, const float* __restrict__ Wn, const float* __restrict__ bn,
    const float* __restrict__ We,
    float* __restrict__ u, float* __restrict__ v, float* __restrict__ node_out){
  __shared__ float ebuf[8][MAXD];               // 4KB: p values
  __shared__ int   sbuf[8][MAXD];               // 4KB
  __shared__ __align__(16) float sh[8][64];     // 2KB
  int wave = threadIdx.x >> 6, lane = threadIdx.x & 63;
  int n = blockIdx.x*8 + wave;        // exact
  int start = offs[n], end = offs[n+1];
  int deg = end - start;
  float ald = al2d[n];

  float sm = 0.f;
  {
    int idx = lane;
    for (int j = start + lane; j < end; j += 64, idx += 64) {
      int r = srcs[j];
      float t = al2s[r] + ald; t = t >= 0.f ? t : 0.2f*t;
      float p = __expf(t); sm += p;
      if (idx < MAXD) { sbuf[wave][idx] = r; ebuf[wave][idx] = p; }
    }
  }
  #pragma unroll
  for (int off = 32; off; off >>= 1) sm += __shfl_xor(sm, off, 64);
  float inv = 1.f/(sm + 1e-16f);

  // aggregation: lane -> (edge-slot es=lane>>3, channel-lane cl=lane&7); uint4 = channels cl*8..cl*8+7
  int cl = lane & 7, es = lane >> 3;
  float acc0 = 0.f, acc1 = 0.f, acc2 = 0.f, acc3 = 0.f;
  float acc4 = 0.f, acc5 = 0.f, acc6 = 0.f, acc7 = 0.f;
  {
    int lim = deg < MAXD ? deg : MAXD;
    const uint4* base4 = (const uint4*)h2pre;   // row = 8 uint4
    #pragma unroll 2
    for (int jj = 0; jj < lim; jj += 8) {
      int idx = jj + es;
      bool ok = idx < lim;
      int idxs = ok ? idx : 0;
      int r = sbuf[wave][idxs];
      float p = ok ? ebuf[wave][idxs] : 0.f;
      uint4 d = base4[(size_t)r*8 + cl];
      acc0 = fmaf(p, bflo(d.x), acc0);
      acc1 = fmaf(p, bfhi(d.x), acc1);
      acc2 = fmaf(p, bflo(d.y), acc2);
      acc3 = fmaf(p, bfhi(d.y), acc3);
      acc4 = fmaf(p, bflo(d.z), acc4);
      acc5 = fmaf(p, bfhi(d.z), acc5);
      acc6 = fmaf(p, bflo(d.w), acc6);
      acc7 = fmaf(p, bfhi(d.w), acc7);
    }
    if (deg > MAXD) {     // rare overflow tail
      for (int jj = MAXD; jj < deg; jj += 8) {
        int idx = jj + es;
        bool ok = idx < deg;
        int j = ok ? (start + idx) : start;
        int r = srcs[j];
        float t = al2s[r] + ald; t = t >= 0.f ? t : 0.2f*t;
        float p = ok ? __expf(t) : 0.f;
        uint4 d = base4[(size_t)r*8 + cl];
        acc0 = fmaf(p, bflo(d.x), acc0);
        acc1 = fmaf(p, bfhi(d.x), acc1);
        acc2 = fmaf(p, bflo(d.y), acc2);
        acc3 = fmaf(p, bfhi(d.y), acc3);
        acc4 = fmaf(p, bflo(d.z), acc4);
        acc5 = fmaf(p, bfhi(d.z), acc5);
        acc6 = fmaf(p, bflo(d.w), acc6);
        acc7 = fmaf(p, bfhi(d.w), acc7);
      }
    }
  }
  // fold the 8 edge-slots (xor butterfly over lane bits 3,4,5); all lanes end with channel sums
  #pragma unroll
  for (int off = 8; off < 64; off <<= 1) {
    acc0 += __shfl_xor(acc0, off, 64);
    acc1 += __shfl_xor(acc1, off, 64);
    acc2 += __shfl_xor(acc2, off, 64);
    acc3 += __shfl_xor(acc3, off, 64);
    acc4 += __shfl_xor(acc4, off, 64);
    acc5 += __shfl_xor(acc5, off, 64);
    acc6 += __shfl_xor(acc6, off, 64);
    acc7 += __shfl_xor(acc7, off, 64);
  }

  float4 b2a = *(const float4*)(b2 + cl*8);
  float4 b2b = *(const float4*)(b2 + cl*8 + 4);
  float o0 = acc0*inv + b2a.x; o0 = o0 > 0.f ? o0 : expm1f(o0);
  float o1 = acc1*inv + b2a.y; o1 = o1 > 0.f ? o1 : expm1f(o1);
  float o2 = acc2*inv + b2a.z; o2 = o2 > 0.f ? o2 : expm1f(o2);
  float o3 = acc3*inv + b2a.w; o3 = o3 > 0.f ? o3 : expm1f(o3);
  float o4 = acc4*inv + b2b.x; o4 = o4 > 0.f ? o4 : expm1f(o4);
  float o5 = acc5*inv + b2b.y; o5 = o5 > 0.f ? o5 : expm1f(o5);
  float o6 = acc6*inv + b2b.z; o6 = o6 > 0.f ? o6 : expm1f(o6);
  float o7 = acc7*inv + b2b.w; o7 = o7 > 0.f ? o7 : expm1f(o7);

  // u[n] = h2 . We[0:64], v[n] = h2 . We[64:128]; lanes 0..7 hold distinct channel groups
  float4 wea = *(const float4*)(We + cl*8);
  float4 web = *(const float4*)(We + cl*8 + 4);
  float4 wva = *(const float4*)(We + 64 + cl*8);
  float4 wvb = *(const float4*)(We + 64 + cl*8 + 4);
  float pu = o0*wea.x + o1*wea.y + o2*wea.z + o3*wea.w
           + o4*web.x + o5*web.y + o6*web.z + o7*web.w;
  float pv = o0*wva.x + o1*wva.y + o2*wva.z + o3*wva.w
           + o4*wvb.x + o5*wvb.y + o6*wvb.z + o7*wvb.w;
  #pragma unroll
  for (int off = 1; off < 8; off <<= 1) { pu += __shfl_xor(pu, off, 64); pv += __shfl_xor(pv, off, 64); }
  if (lane == 0) { u[n] = pu; v[n] = pv; }

  if (es == 0) {
    *(float4*)&sh[wave][cl*8]     = make_float4(o0, o1, o2, o3);
    *(float4*)&sh[wave][cl*8 + 4] = make_float4(o4, o5, o6, o7);
  }
  __syncthreads();

  // node_out = h2 @ Wn + bn  (Wn: [64,32]); lanes split k-range in halves
  int jcol = lane & 31, half = lane >> 5;
  float a2 = 0.f;
  #pragma unroll 8
  for (int k2 = 0; k2 < 32; k2++) {
    int k = half*32 + k2;
    a2 = fmaf(sh[wave][k], Wn[k*32 + jcol], a2);
  }
  a2 += __shfl_xor(a2, 32, 64);
  if (lane < 32) node_out[(size_t)n*32 + lane] = a2 + bn[jcol];
}

// ---------------- Edge head: out = u[row] + v[col] + edge_attr . We[128:144] + be ----------------
__global__ __launch_bounds__(256) void edge_kernel(const int* __restrict__ ei, const float* __restrict__ ea,
    const float* __restrict__ u, const float* __restrict__ v,
    const float* __restrict__ We, const float* __restrict__ be, float* __restrict__ out){
  int k = blockIdx.x*256 + threadIdx.x;   // grid is exact: 800000/256
  int r = ei[k], c = ei[N_EDGES + k];
  float val = u[r] + v[c] + be[0];
  const float4* wp = (const float4*)(We + 128);
  const float4* p  = (const float4*)(ea + (size_t)k*16);
  #pragma unroll
  for (int jj = 0; jj < 4; jj++) {
    float4 q = p[jj], wq = wp[jj];
    val = fmaf(q.x, wq.x, val);
    val = fmaf(q.y, wq.y, val);
    val = fmaf(q.z, wq.z, val);
    val = fmaf(q.w, wq.w, val);
  }
  out[k] = val;
}

extern "C" void kernel_launch(void* const* d_in, const int* in_sizes, int n_in,
                              void* d_out, int out_size, void* d_ws, size_t ws_size,
                              hipStream_t stream) {
  const float* x   = (const float*)d_in[0];
  const int*   ei  = (const int*)d_in[1];
  const float* ea  = (const float*)d_in[2];
  const float* W1  = (const float*)d_in[3];
  const float* a1s = (const float*)d_in[4];
  const float* a1d = (const float*)d_in[5];
  const float* b1  = (const float*)d_in[6];
  const float* W2  = (const float*)d_in[7];
  const float* a2s = (const float*)d_in[8];
  const float* a2d = (const float*)d_in[9];
  const float* b2  = (const float*)d_in[10];
  const float* Wn  = (const float*)d_in[11];
  const float* bn  = (const float*)d_in[12];
  const float* We  = (const float*)d_in[13];
  const float* be  = (const float*)d_in[14];
  float* out = (float*)d_out;

  // ---- workspace layout, peak 64,000,224 B (unchanged), 16B-aligned ----
  char* w = (char*)d_ws;
  int*   offs   = (int*)(w);                        //       0 .. 200,016
  int*   cnt    = (int*)(w + 200016);               // 200,016 .. 400,016 (wf1/ws1/wd1 alias after scans)
  int*   bcur   = (int*)(w + 400016);               // 784 B bucket cursors (wf2 aliases after lscatter)
  int*   srcs   = (int*)(w + 600016);               // 600,016 .. 4,000,016
  float* al1s   = (float*)(w + 4000016);            // [N,4] fp32, .. 4,800,016
  float* al1d   = (float*)(w + 4800016);            // [N,4] fp32, .. 5,600,016
  float* al2s   = (float*)(w + 5600016);            // [N] fp32,  .. 5,800,016
  float* al2d   = (float*)(w + 5800016);            // .. 6,000,016
  float* uu     = (float*)(w + 6000016);            // .. 6,200,016
  float* vv     = (float*)(w + 6200016);            // .. 6,400,016
  bf16*  h2pre  = (bf16*)(w + 6400016);             // [N,64] bf16, .. 12,800,016 (xb aliases BEFORE gemm2)
  bf16*  ag     = (bf16*)(w + 12800016);            // [N,256] bf16 aggregate, .. 38,400,016
  int*   psum   = (int*)(w + 38400016);             // 49 partials .. 38,400,212
  bf16*  h1     = (bf16*)(w + 38400224);            // [N,256] bf16, .. 64,000,224
  unsigned short* wf1 = (unsigned short*)cnt;       // 32,768 B  (cnt dead after scanC)
  float* ws1 = (float*)(w + 232784);                // 1KB, inside cnt region after wf1
  float* wd1 = (float*)(w + 233808);                // 1KB
  unsigned short* wf2 = (unsigned short*)bcur;      // 32,768 B  (bcur dead after lscatter)
  unsigned short* xb  = (unsigned short*)h2pre;     // [N,64] bf16 x-table; dead before gemm2 writes h2pre
  unsigned int* pairbuf = (unsigned int*)h1;        // 6.4 MB bucket regions (h1 dead until gemm1b)

  const int NPART = (N_NODES + 1023) / 1024;        // 49

  initb_kernel     <<<1, 256, 0, stream>>>(bcur);
  binscatter_kernel<<<(N_TOT + 4095)/4096, 256, 0, stream>>>(ei, bcur, pairbuf);
  bcount_kernel    <<<NBUCK, 256, 0, stream>>>(pairbuf, bcur, cnt);
  scanA_kernel     <<<NPART, 1024, 0, stream>>>(cnt, psum);
  scanB_kernel     <<<1, 64, 0, stream>>>(psum, NPART);
  scanC_kernel     <<<NPART, 1024, 0, stream>>>(cnt, psum, offs);
  lscatter_kernel  <<<NBUCK, 256, 0, stream>>>(pairbuf, bcur, offs, srcs);
  wfrag_kernel     <<<129, 256, 0, stream>>>(W1, W2, a1s, a1d, wf1, wf2, ws1, wd1);
  xprep_kernel     <<<N_NODES/16, 256, 0, stream>>>(x, ws1, wd1, xb, al1s, al1d);
  attn1x_kernel    <<<N_NODES/4, 256, 0, stream>>>(xb, al1s, al1d, offs, srcs, ag);
  gemm1b_kernel    <<<(N_NODES + 63)/64, 256, 0, stream>>>((const unsigned short*)ag, wf1, b1, h1);
  gemm2_kernel     <<<(N_NODES + 63)/64, 256, 0, stream>>>(h1, wf2, a2s, a2d, h2pre, al2s, al2d);
  attn2_kernel     <<<N_NODES/8, 512, 0, stream>>>(h2pre, al2s, al2d, offs, srcs, b2, Wn, bn, We,
                                                   uu, vv, out);
  edge_kernel      <<<N_EDGES/256, 256, 0, stream>>>(ei, ea, uu, vv, We, be, out + (size_t)N_NODES*32);
}